// Round 17
// baseline (295.589 us; speedup 1.0000x reference)
//
#include <hip/hip_runtime.h>
#include <hip/hip_bf16.h>
#include <math.h>

// B=2, S=2048, H=2048, NH=16, HD=128
#define SEQ 2048
#define HID 2048
#define NHEAD 16
#define HDIM 128
#define LDK 4096   // fused QK row stride

typedef __bf16 bf16_t;
typedef __bf16 bf16x2 __attribute__((ext_vector_type(2)));
typedef __bf16 bf16x4_t __attribute__((ext_vector_type(4)));
typedef __bf16 bf16x8 __attribute__((ext_vector_type(8)));
typedef float f32x4 __attribute__((ext_vector_type(4)));
typedef float f32x16 __attribute__((ext_vector_type(16)));
typedef unsigned u32x4 __attribute__((ext_vector_type(4)));

#define MFMA16(a, b, c) __builtin_amdgcn_mfma_f32_16x16x32_bf16(a, b, c, 0, 0, 0)
#define MFMA32(a, b, c) __builtin_amdgcn_mfma_f32_32x32x16_bf16(a, b, c, 0, 0, 0)
#define GLOAD_LDS(g, l) \
  __builtin_amdgcn_global_load_lds((const __attribute__((address_space(1))) void*)(g), \
                                   (__attribute__((address_space(3))) void*)(l), 16, 0, 0)

static __device__ inline unsigned pk2(float lo, float hi) {
  bf16x2 t; t[0] = (bf16_t)lo; t[1] = (bf16_t)hi;
  return __builtin_bit_cast(unsigned, t);
}

// native 2^x (v_exp_f32 computes exp2); avoids glibc __exp2f macro collision
static __device__ inline float exp2_fast(float x) {
  float r;
  asm("v_exp_f32 %0, %1" : "=v"(r) : "v"(x));
  return r;
}

// pack 8 p-values into the PV B-fragment via v_permlane32_swap (verified R13).
// NOTE: safe here because the two operands hold DIFFERENT values (A,B) and both
// outputs are consumed, so the allocator cannot coalesce vdst/vsrc. The same-value
// variant (R16's swap_half) coalesced to one register and corrupted results.
static __device__ inline bf16x8 pack_slice(const float* p) {
  unsigned A1 = pk2(p[0], p[1]);
  unsigned A2 = pk2(p[2], p[3]);
  unsigned B1 = pk2(p[4], p[5]);
  unsigned B2 = pk2(p[6], p[7]);
  asm("v_permlane32_swap_b32 %0, %1" : "+v"(A1), "+v"(B1));
  asm("v_permlane32_swap_b32 %0, %1" : "+v"(A2), "+v"(B2));
  u32x4 W = {A1, A2, B1, B2};
  return __builtin_bit_cast(bf16x8, W);
}

// ---------------- merged cast kernel: hidden (f32->bf16) + 4 weights ----------------
__global__ void cast_all(const float* __restrict__ hidden,
                         const float* __restrict__ wq, const float* __restrict__ wk,
                         const float* __restrict__ wv, const float* __restrict__ wo,
                         bf16_t* __restrict__ hOut, bf16_t* __restrict__ wOut) {
  int blk = blockIdx.x;
  const float* src;
  bf16_t* dst;
  int i;
  if (blk < 8192) {
    src = hidden; dst = hOut;
    i = blk * 256 + threadIdx.x;
  } else {
    int w = (blk - 8192) >> 12;
    const float* srcs[4] = {wq, wk, wv, wo};
    src = srcs[w];
    dst = wOut + (size_t)w * (HID * HID);
    i = ((blk - 8192) & 4095) * 256 + threadIdx.x;
  }
  float4 v = ((const float4*)src)[i];
  bf16x4_t b;
  b[0] = (bf16_t)v.x; b[1] = (bf16_t)v.y; b[2] = (bf16_t)v.z; b[3] = (bf16_t)v.w;
  ((bf16x4_t*)dst)[i] = b;
}

// ---------------- 256x256 8-phase GEMM + fused RoPE epilogue (QK projection) -------
__global__ __launch_bounds__(512, 2) void gemm256_rope(
    const bf16_t* __restrict__ A, const bf16_t* __restrict__ Bw,
    bf16_t* __restrict__ Cb, const float* __restrict__ cosT,
    const float* __restrict__ sinT, int M, int N, int K) {
  __shared__ char smem[131072];
  const int tid = threadIdx.x, lane = tid & 63, wid = tid >> 6;
  const int wr = wid >> 2, wc = wid & 3;
  const int lr = lane & 15, lg = lane >> 4;
  const int xcd = blockIdx.x & 7, l = blockIdx.x >> 3;
  const int brow = (xcd >> 2) * 8 + (l >> 2);
  const int bcol = (xcd & 3) * 4 + (l & 3);
  const int NT = K >> 6;

  const bf16_t* Ab = A + (size_t)(brow * 256) * K;
  const bf16_t* Bb = Bw + (size_t)(bcol * 256) * K;

  f32x4 acc[8][4] = {};
  bf16x8 af[4], bfr[4];
  const int swz = (lg ^ ((lr >> 1) & 3)) << 4;

#define STAGE_HALF(t_, op, kh)                                                        \
  {                                                                                   \
    int tt = (t_) < NT ? (t_) : NT - 1;                                               \
    const bf16_t* gsrc = (op) ? Bb : Ab;                                              \
    char* ldst = smem + (tt & 1) * 65536 + (op) * 32768 + (kh) * 16384;               \
    _Pragma("unroll") for (int is = 0; is < 2; ++is) {                                \
      int p = tid + is * 512;                                                         \
      int row = p >> 2, ch = p & 3;                                                   \
      GLOAD_LDS(gsrc + (size_t)row * K + tt * 64 + (kh) * 32 +                        \
                    ((ch ^ ((row >> 1) & 3)) * 8),                                    \
                ldst + p * 16);                                                       \
    }                                                                                 \
  }

#define PHASE(cb, kh, mh, LOADB, STAGECALL, VM)                                       \
  {                                                                                   \
    _Pragma("unroll") for (int mf = 0; mf < 4; ++mf) {                                \
      int row = wr * 128 + (mh) * 64 + mf * 16 + lr;                                  \
      af[mf] = *(const bf16x8*)(smem + (cb) * 65536 + (kh) * 16384 + row * 64 + swz); \
    }                                                                                 \
    if (LOADB) {                                                                      \
      _Pragma("unroll") for (int nf = 0; nf < 4; ++nf) {                              \
        int row = wc * 64 + nf * 16 + lr;                                             \
        bfr[nf] = *(const bf16x8*)(smem + (cb) * 65536 + 32768 + (kh) * 16384 +       \
                                   row * 64 + swz);                                   \
      }                                                                               \
    }                                                                                 \
    STAGECALL;                                                                        \
    __builtin_amdgcn_s_barrier();                                                     \
    asm volatile("s_waitcnt lgkmcnt(0)" ::: "memory");                                \
    __builtin_amdgcn_sched_barrier(0);                                                \
    __builtin_amdgcn_s_setprio(1);                                                    \
    _Pragma("unroll") for (int mf = 0; mf < 4; ++mf)                                  \
      _Pragma("unroll") for (int nf = 0; nf < 4; ++nf)                                \
        acc[(mh) * 4 + mf][nf] = MFMA16(af[mf], bfr[nf], acc[(mh) * 4 + mf][nf]);     \
    __builtin_amdgcn_s_setprio(0);                                                    \
    if (VM) { asm volatile("s_waitcnt vmcnt(6)" ::: "memory"); }                      \
    __builtin_amdgcn_s_barrier();                                                     \
    __builtin_amdgcn_sched_barrier(0);                                                \
  }

  STAGE_HALF(0, 1, 0); STAGE_HALF(0, 0, 0); STAGE_HALF(0, 1, 1); STAGE_HALF(0, 0, 1);
  STAGE_HALF(1, 1, 0); STAGE_HALF(1, 0, 0); STAGE_HALF(1, 1, 1);
  asm volatile("s_waitcnt vmcnt(6)" ::: "memory");
  __builtin_amdgcn_s_barrier();
  __builtin_amdgcn_sched_barrier(0);

  const int NI = NT >> 1;
  for (int i = 0; i < NI; ++i) {
    const int t2 = 2 * i;
    PHASE(0, 0, 0, 1, STAGE_HALF(t2 + 1, 0, 1), 0);
    PHASE(0, 0, 1, 0, STAGE_HALF(t2 + 2, 1, 0), 0);
    PHASE(0, 1, 0, 1, STAGE_HALF(t2 + 2, 0, 0), 0);
    PHASE(0, 1, 1, 0, STAGE_HALF(t2 + 2, 1, 1), 1);
    PHASE(1, 0, 0, 1, STAGE_HALF(t2 + 2, 0, 1), 0);
    PHASE(1, 0, 1, 0, STAGE_HALF(t2 + 3, 1, 0), 0);
    PHASE(1, 1, 0, 1, STAGE_HALF(t2 + 3, 0, 0), 0);
    PHASE(1, 1, 1, 0, STAGE_HALF(t2 + 3, 1, 1), 1);
  }
#undef PHASE
#undef STAGE_HALF

  // ---- fused RoPE epilogue ----
  asm volatile("s_waitcnt vmcnt(0)" ::: "memory");
  __builtin_amdgcn_s_barrier();

  const int base = wid * 16384;
#pragma unroll
  for (int mi = 0; mi < 8; ++mi)
#pragma unroll
    for (int nf = 0; nf < 4; ++nf)
#pragma unroll
      for (int r = 0; r < 4; ++r)
        *(bf16_t*)(smem + base + ((mi * 4 + nf) * 4 + r) * 128 + lane * 2) =
            (bf16_t)acc[mi][nf][r];
  __syncthreads();

  const int pbase = (wid ^ 1) * 16384;
  const float SCALE = 0.12751569978848444f;  // log2(e)/sqrt(128) for Q columns
#pragma unroll
  for (int mi = 0; mi < 8; ++mi)
#pragma unroll
    for (int nf = 0; nf < 4; ++nf) {
      int col = bcol * 256 + wc * 64 + nf * 16 + lr;
      int d = col & 127;
      const float sc = (col < 2048) ? SCALE : 1.0f;
#pragma unroll
      for (int r = 0; r < 4; ++r) {
        int row = brow * 256 + wr * 128 + (mi >> 2) * 64 + (mi & 3) * 16 + lg * 4 + r;
        int s = row & (SEQ - 1);
        float part = (float)*(const bf16_t*)(smem + pbase +
                                             ((mi * 4 + nf) * 4 + r) * 128 + lane * 2);
        float cc = cosT[s * HDIM + d];
        float ss = sinT[s * HDIM + d];
        float own = acc[mi][nf][r];
        float ov = (d < 64) ? (own * cc - part * ss) : (own * cc + part * ss);
        Cb[(size_t)row * N + col] = (bf16_t)(ov * sc);
      }
    }
}

// ---------------- V GEMM + fused transpose epilogue: writes Vt[b][h][d][s] ---------
__global__ __launch_bounds__(256, 3) void gemm_v(
    const bf16_t* __restrict__ A, const bf16_t* __restrict__ Bw,
    bf16_t* __restrict__ Vt, int M, int N, int K) {
  __shared__ char smv[34816];
  bf16_t* As = (bf16_t*)smv;
  bf16_t* Bs = (bf16_t*)(smv + 16384);
  const int tid = threadIdx.x;
  const int lane = tid & 63, wid = tid >> 6;
  const int wr = wid >> 1, wc = wid & 1;
  const int lr = lane & 15, lg = lane >> 4;
  const int nwg = gridDim.x;
  const int lid = (blockIdx.x & 7) * (nwg >> 3) + (blockIdx.x >> 3);
  const int nbc = N >> 7;
  const int brow = lid / nbc, bcol = lid % nbc;

  f32x4 acc[4][4] = {};
  const int swz = lg ^ ((lr >> 1) & 3);

  const int srow = tid >> 2, sch = tid & 3;
#define GSTAGE(k0, bb)                                                                   \
  {                                                                                      \
    _Pragma("unroll") for (int is = 0; is < 2; ++is) {                                   \
      int row = srow + is * 64;                                                          \
      int g = (sch ^ ((row >> 1) & 3)) * 8;                                              \
      GLOAD_LDS(A + (size_t)(brow * 128 + row) * K + (k0) + g,                           \
                As + (bb) * 4096 + (row * 4 + sch) * 8);                                 \
      GLOAD_LDS(Bw + (size_t)(bcol * 128 + row) * K + (k0) + g,                          \
                Bs + (bb) * 4096 + (row * 4 + sch) * 8);                                 \
    }                                                                                    \
  }

  GSTAGE(0, 0);
  __syncthreads();

  const int nt = K / 32;
  for (int t = 0; t < nt; ++t) {
    const int cb = t & 1;
    if (t + 1 < nt) GSTAGE((t + 1) * 32, cb ^ 1);
    bf16x8 af[4], bfr[4];
#pragma unroll
    for (int m = 0; m < 4; ++m)
      af[m] = *(const bf16x8*)(As + cb * 4096 + (wr * 64 + m * 16 + lr) * 32 + swz * 8);
#pragma unroll
    for (int n = 0; n < 4; ++n)
      bfr[n] = *(const bf16x8*)(Bs + cb * 4096 + (wc * 64 + n * 16 + lr) * 32 + swz * 8);
#pragma unroll
    for (int m = 0; m < 4; ++m)
#pragma unroll
      for (int n = 0; n < 4; ++n)
        acc[m][n] = MFMA16(af[m], bfr[n], acc[m][n]);
    __syncthreads();
  }
#undef GSTAGE

  // ---- fused transpose epilogue ----
  bf16_t* tr = (bf16_t*)smv;                   // [128 d][136 s-capacity]
#pragma unroll
  for (int m = 0; m < 4; ++m)
#pragma unroll
    for (int n = 0; n < 4; ++n) {
      int d = wc * 64 + n * 16 + lr;
#pragma unroll
      for (int r = 0; r < 4; ++r) {
        int s = wr * 64 + m * 16 + lg * 4 + r;
        tr[d * 136 + s] = (bf16_t)acc[m][n][r];
      }
    }
  __syncthreads();

  const int b = brow >> 4, h = bcol;
  const int s0 = (brow & 15) * 128;
  bf16_t* vbase = Vt + ((size_t)(b * NHEAD + h) * HDIM) * SEQ + s0;
  const int dd = (lane >> 3);
  const int sl = (lane & 7) * 8;
#pragma unroll
  for (int it = 0; it < 4; ++it) {
    int d = wid * 32 + it * 8 + dd;
#pragma unroll
    for (int si = 0; si < 2; ++si) {
      int s = si * 64 + sl;
      bf16x8 v = *(const bf16x8*)(tr + d * 136 + s);
      *(bf16x8*)(vbase + (size_t)d * SEQ + s) = v;
    }
  }
}

// ---------------- GEMM: C = A * B^T, 2-phase double-buffered (128x128) -------------
__global__ __launch_bounds__(256, 3) void gemm_bt(
    const bf16_t* __restrict__ A, const bf16_t* __restrict__ Bw,
    bf16_t* __restrict__ Cb, float* __restrict__ Cf,
    int M, int N, int K) {
  __shared__ bf16_t As[2][128 * 32];
  __shared__ bf16_t Bs[2][128 * 32];
  const int tid = threadIdx.x;
  const int lane = tid & 63, wid = tid >> 6;
  const int wr = wid >> 1, wc = wid & 1;
  const int lr = lane & 15, lg = lane >> 4;
  const int nwg = gridDim.x;
  const int lid = (blockIdx.x & 7) * (nwg >> 3) + (blockIdx.x >> 3);
  const int nbc = N >> 7;
  const int brow = lid / nbc, bcol = lid % nbc;

  f32x4 acc[4][4] = {};
  const int swz = lg ^ ((lr >> 1) & 3);

  const int srow = tid >> 2, sch = tid & 3;
#define GSTAGE(k0, bb)                                                                   \
  {                                                                                      \
    _Pragma("unroll") for (int is = 0; is < 2; ++is) {                                   \
      int row = srow + is * 64;                                                          \
      int g = (sch ^ ((row >> 1) & 3)) * 8;                                              \
      GLOAD_LDS(A + (size_t)(brow * 128 + row) * K + (k0) + g,                           \
                &As[bb][(row * 4 + sch) * 8]);                                           \
      GLOAD_LDS(Bw + (size_t)(bcol * 128 + row) * K + (k0) + g,                          \
                &Bs[bb][(row * 4 + sch) * 8]);                                           \
    }                                                                                    \
  }

  GSTAGE(0, 0);
  __syncthreads();

  const int nt = K / 32;
  for (int t = 0; t < nt; ++t) {
    const int cb = t & 1;
    if (t + 1 < nt) GSTAGE((t + 1) * 32, cb ^ 1);
    bf16x8 af[4], bfr[4];
#pragma unroll
    for (int m = 0; m < 4; ++m)
      af[m] = *(const bf16x8*)(&As[cb][(wr * 64 + m * 16 + lr) * 32 + swz * 8]);
#pragma unroll
    for (int n = 0; n < 4; ++n)
      bfr[n] = *(const bf16x8*)(&Bs[cb][(wc * 64 + n * 16 + lr) * 32 + swz * 8]);
#pragma unroll
    for (int m = 0; m < 4; ++m)
#pragma unroll
      for (int n = 0; n < 4; ++n)
        acc[m][n] = MFMA16(af[m], bfr[n], acc[m][n]);
    __syncthreads();
  }
#undef GSTAGE

#pragma unroll
  for (int m = 0; m < 4; ++m)
#pragma unroll
    for (int n = 0; n < 4; ++n)
#pragma unroll
      for (int r = 0; r < 4; ++r) {
        int row = brow * 128 + wr * 64 + m * 16 + lg * 4 + r;
        int col = bcol * 128 + wc * 64 + n * 16 + lr;
        float v = acc[m][n][r];
        if (Cf) Cf[(size_t)row * N + col] = v;
        else    Cb[(size_t)row * N + col] = (bf16_t)v;
      }
}

// ---------------- mask pack: mask f32 -> maskP[b][kg][q][kl'] bf16, x log2e ---------
__global__ void mask_pack(const float* __restrict__ m, bf16_t* __restrict__ mp) {
  const float L2E = 1.4426950408889634f;
  __shared__ float t[32][33];
  int tx = threadIdx.x & 31, ty = threadIdx.x >> 5;
  int q0 = blockIdx.x * 32, k0 = blockIdx.y * 32;
  const float* mb = m + (size_t)blockIdx.z * SEQ * SEQ;
#pragma unroll
  for (int j = 0; j < 4; ++j)
    t[ty + j * 8][tx] = mb[(size_t)(q0 + ty + j * 8) * SEQ + k0 + tx];
  __syncthreads();
  int r = tx & 15, hi = tx >> 4;
  int kl = (r & 3) + 8 * (r >> 2) + 4 * hi;
  bf16_t* ob = mp + ((size_t)(blockIdx.z * 64 + blockIdx.y) * 2048 + q0) * 32;
#pragma unroll
  for (int j = 0; j < 4; ++j) {
    int qloc = ty + j * 8;
    ob[(size_t)qloc * 32 + tx] = (bf16_t)(t[qloc][kl] * L2E);
  }
}

// ---------------- flash attention fwd v8b: 2-chain QK, verified shfl max ------------
// = R15-verified v7 + each kb's QK as two independent 4-deep MFMA chains (halved
// serial latency). Row-max exchange stays on the VERIFIED __shfl_xor path (R16's
// same-value permlane variant corrupted results via vdst/vsrc coalescing).
__global__ __launch_bounds__(512, 2) void flash_fwd(
    const bf16_t* __restrict__ Qf, const bf16_t* __restrict__ Kf,
    const bf16_t* __restrict__ Vt, const bf16_t* __restrict__ maskP,
    bf16_t* __restrict__ AO) {
  __shared__ char smem[131072];          // K 2x32K | V 2x32K
  char* KsB = smem;
  char* VsB = smem + 65536;
  const int tid = threadIdx.x, lane = tid & 63, wid = tid >> 6;
  const int q32 = lane & 31, hi = lane >> 5;

  const int x = blockIdx.x;
  const int bh = x & 31, qt = x >> 5;          // qt 0..7
  const int b = bh >> 4, h = bh & 15;
  const int qg = qt * 256 + wid * 32 + q32;

  bf16x8 qf[8];
  const bf16_t* qptr = Qf + (size_t)(b * SEQ + qg) * LDK + h * HDIM + hi * 8;
#pragma unroll
  for (int ds = 0; ds < 8; ++ds) qf[ds] = *(const bf16x8*)(qptr + ds * 16);

  const bf16_t* mQ = maskP + (size_t)b * 64 * 65536 + (size_t)qg * 32 + hi * 16;

  float mrun = -INFINITY, lpart = 0.f;
  f32x16 o[4] = {};
  const int lswz = (q32 & 15) << 4;

#define STAGE_KV(kt_, bb)                                                                \
  {                                                                                      \
    const int kb0_ = (kt_) * 128;                                                        \
    _Pragma("unroll") for (int is = 0; is < 4; ++is) {                                   \
      int p = tid + is * 512;                                                            \
      int row = p >> 4, ch = p & 15;                                                     \
      int src = (ch * 16) ^ ((row & 15) << 4);                                           \
      GLOAD_LDS((const char*)(Kf + (size_t)(b * SEQ + kb0_ + row) * LDK + h * HDIM) +    \
                    src,                                                                 \
                KsB + (bb) * 32768 + p * 16);                                            \
      GLOAD_LDS((const char*)(Vt + (size_t)(bh * HDIM + row) * SEQ + kb0_) + src,        \
                VsB + (bb) * 32768 + p * 16);                                            \
    }                                                                                    \
  }

#define INIT_SACC(kb)                                                                    \
  {                                                                                      \
    _Pragma("unroll") for (int r = 0; r < 8; ++r) {                                      \
      sacc[kb][r]     = (float)mk[2 * (kb)][r];                                          \
      sacc[kb][8 + r] = (float)mk[2 * (kb) + 1][r];                                      \
    }                                                                                    \
  }
  // two independent 4-deep chains, merged with 16 v_add_f32
#define QK_CHAIN(kb)                                                                     \
  {                                                                                      \
    const char* Kb_ = KsB + cur * 32768 + q32 * 256 + (kb) * 8192;                       \
    f32x16 sb = {};                                                                      \
    __builtin_amdgcn_s_setprio(1);                                                       \
    _Pragma("unroll") for (int ds = 0; ds < 4; ++ds) {                                   \
      bf16x8 ka = *(const bf16x8*)(Kb_ + ((ds * 32 + hi * 16) ^ lswz));                  \
      bf16x8 kb2 = *(const bf16x8*)(Kb_ + (((ds + 4) * 32 + hi * 16) ^ lswz));           \
      sacc[kb] = MFMA32(ka, qf[ds], sacc[kb]);                                           \
      sb = MFMA32(kb2, qf[ds + 4], sb);                                                  \
    }                                                                                    \
    __builtin_amdgcn_s_setprio(0);                                                       \
    _Pragma("unroll") for (int r = 0; r < 16; ++r) sacc[kb][r] += sb[r];                 \
  }

  STAGE_KV(0, 0);
  __syncthreads();

  const int NT = SEQ / 128;                     // 16
  for (int kt = 0; kt < NT; ++kt) {
    const int cur = kt & 1;
    if (kt + 1 < NT) STAGE_KV(kt + 1, cur ^ 1);

    bf16x8 mk[8];
#pragma unroll
    for (int kb = 0; kb < 4; ++kb) {
      const size_t mo = (size_t)(kt * 4 + kb) * 65536;
      mk[2 * kb]     = *(const bf16x8*)(mQ + mo);
      mk[2 * kb + 1] = *(const bf16x8*)(mQ + mo + 8);
    }

    f32x16 sacc[4];
    INIT_SACC(0);
    QK_CHAIN(0);

#pragma unroll
    for (int kb = 0; kb < 4; ++kb) {
      if (kb < 3) {
        INIT_SACC(kb + 1);
        QK_CHAIN(kb + 1);
      }

      float a0 = fmaxf(fmaxf(sacc[kb][0], sacc[kb][1]), fmaxf(sacc[kb][2], sacc[kb][3]));
      float a1 = fmaxf(fmaxf(sacc[kb][4], sacc[kb][5]), fmaxf(sacc[kb][6], sacc[kb][7]));
      float a2 = fmaxf(fmaxf(sacc[kb][8], sacc[kb][9]), fmaxf(sacc[kb][10], sacc[kb][11]));
      float a3 = fmaxf(fmaxf(sacc[kb][12], sacc[kb][13]),
                       fmaxf(sacc[kb][14], sacc[kb][15]));
      float mx = fmaxf(fmaxf(a0, a1), fmaxf(a2, a3));
      mx = fmaxf(mx, __shfl_xor(mx, 32, 64));   // verified cross-half max
      if (!__all(mx <= mrun + 11.5f)) {          // e^8-equivalent bound in base-2
        float mnew = fmaxf(mrun, mx);
        float corr = exp2_fast(mrun - mnew);
        mrun = mnew; lpart *= corr;
#pragma unroll
        for (int d0 = 0; d0 < 4; ++d0)
#pragma unroll
          for (int r = 0; r < 16; ++r) o[d0][r] *= corr;
      }

      float p_[16];
#pragma unroll
      for (int r = 0; r < 16; ++r) p_[r] = exp2_fast(sacc[kb][r] - mrun);
      {
        float t0 = (p_[0] + p_[1]) + (p_[2] + p_[3]);
        float t1 = (p_[4] + p_[5]) + (p_[6] + p_[7]);
        float t2 = (p_[8] + p_[9]) + (p_[10] + p_[11]);
        float t3 = (p_[12] + p_[13]) + (p_[14] + p_[15]);
        lpart += (t0 + t1) + (t2 + t3);
      }

      const char* Vbase = VsB + cur * 32768 + q32 * 256;
#pragma unroll
      for (int s = 0; s < 2; ++s) {
        bf16x8 pav = pack_slice(p_ + 8 * s);
        const int gs = kb * 2 + s;
        __builtin_amdgcn_s_setprio(1);
#pragma unroll
        for (int d0 = 0; d0 < 4; ++d0) {
          bf16x8 vf = *(const bf16x8*)(Vbase + d0 * 8192 +
                                       ((gs * 32 + hi * 16) ^ lswz));
          o[d0] = MFMA32(vf, pav, o[d0]);
        }
        __builtin_amdgcn_s_setprio(0);
      }
    }
    __syncthreads();
  }
#undef STAGE_KV
#undef INIT_SACC
#undef QK_CHAIN

  float l = lpart + __shfl_xor(lpart, 32, 64);
  float rl = 1.f / l;
  bf16_t* aorow = AO + (size_t)(b * SEQ + qg) * HID + h * HDIM;
#pragma unroll
  for (int d0 = 0; d0 < 4; ++d0)
#pragma unroll
    for (int g = 0; g < 4; ++g) {
      unsigned lo = pk2(o[d0][4 * g + 0] * rl, o[d0][4 * g + 1] * rl);
      unsigned hi2 = pk2(o[d0][4 * g + 2] * rl, o[d0][4 * g + 3] * rl);
      int d = d0 * 32 + 8 * g + 4 * hi;
      *(unsigned*)(aorow + d) = lo;
      *(unsigned*)(aorow + d + 2) = hi2;
    }
}

// ---------------- launch ----------------
extern "C" void kernel_launch(void* const* d_in, const int* in_sizes, int n_in,
                              void* d_out, int out_size, void* d_ws, size_t ws_size,
                              hipStream_t stream) {
  const float* hidden = (const float*)d_in[0];
  const float* cost   = (const float*)d_in[1];
  const float* sint   = (const float*)d_in[2];
  const float* mask   = (const float*)d_in[3];
  const float* Wq     = (const float*)d_in[4];
  const float* Wk     = (const float*)d_in[5];
  const float* Wv     = (const float*)d_in[6];
  const float* Wo     = (const float*)d_in[7];
  float* out = (float*)d_out;
  char* ws = (char*)d_ws;

  bf16_t* Af    = (bf16_t*)(ws + 0);
  bf16_t* Wqb   = (bf16_t*)(ws + 16777216);
  bf16_t* Wvb   = (bf16_t*)(ws + 33554432);
  bf16_t* Wob   = (bf16_t*)(ws + 41943040);
  bf16_t* QK    = (bf16_t*)(ws + 50331648);
  bf16_t* maskP = (bf16_t*)(ws + 83886080);
  bf16_t* Vt    = (bf16_t*)(ws + 100663296);
  bf16_t* AO    = (bf16_t*)(ws + 16777216);

  cast_all<<<24576, 256, 0, stream>>>(hidden, Wq, Wk, Wv, Wo, Af, Wqb);

  gemm256_rope<<<256, 512, 0, stream>>>(Af, Wqb, QK, cost, sint, 4096, LDK, HID);
  gemm_v<<<512, 256, 0, stream>>>(Af, Wvb, Vt, 4096, HID, HID);

  mask_pack<<<dim3(64, 64, 2), 256, 0, stream>>>(mask, maskP);

  flash_fwd<<<256, 512, 0, stream>>>(QK, QK + 2048, Vt, maskP, AO);

  gemm_bt<<<512, 256, 0, stream>>>(AO, Wob, nullptr, out, 4096, HID, HID);
}

// Round 18
// 292.595 us; speedup vs baseline: 1.0102x; 1.0102x over previous
//
#include <hip/hip_runtime.h>
#include <hip/hip_bf16.h>
#include <math.h>

// B=2, S=2048, H=2048, NH=16, HD=128
#define SEQ 2048
#define HID 2048
#define NHEAD 16
#define HDIM 128
#define LDK 4096   // fused QK row stride

typedef __bf16 bf16_t;
typedef __bf16 bf16x2 __attribute__((ext_vector_type(2)));
typedef __bf16 bf16x4_t __attribute__((ext_vector_type(4)));
typedef __bf16 bf16x8 __attribute__((ext_vector_type(8)));
typedef float f32x4 __attribute__((ext_vector_type(4)));
typedef float f32x16 __attribute__((ext_vector_type(16)));
typedef unsigned u32x4 __attribute__((ext_vector_type(4)));

#define MFMA16(a, b, c) __builtin_amdgcn_mfma_f32_16x16x32_bf16(a, b, c, 0, 0, 0)
#define MFMA32(a, b, c) __builtin_amdgcn_mfma_f32_32x32x16_bf16(a, b, c, 0, 0, 0)
#define GLOAD_LDS(g, l) \
  __builtin_amdgcn_global_load_lds((const __attribute__((address_space(1))) void*)(g), \
                                   (__attribute__((address_space(3))) void*)(l), 16, 0, 0)

static __device__ inline unsigned pk2(float lo, float hi) {
  bf16x2 t; t[0] = (bf16_t)lo; t[1] = (bf16_t)hi;
  return __builtin_bit_cast(unsigned, t);
}

// native 2^x (v_exp_f32 computes exp2); avoids glibc __exp2f macro collision
static __device__ inline float exp2_fast(float x) {
  float r;
  asm("v_exp_f32 %0, %1" : "=v"(r) : "v"(x));
  return r;
}

// pack 8 p-values into the PV B-fragment via v_permlane32_swap (verified R13).
// Safe because the two operands hold DIFFERENT values and both outputs are used.
static __device__ inline bf16x8 pack_slice(const float* p) {
  unsigned A1 = pk2(p[0], p[1]);
  unsigned A2 = pk2(p[2], p[3]);
  unsigned B1 = pk2(p[4], p[5]);
  unsigned B2 = pk2(p[6], p[7]);
  asm("v_permlane32_swap_b32 %0, %1" : "+v"(A1), "+v"(B1));
  asm("v_permlane32_swap_b32 %0, %1" : "+v"(A2), "+v"(B2));
  u32x4 W = {A1, A2, B1, B2};
  return __builtin_bit_cast(bf16x8, W);
}

// ---------------- merged cast kernel: hidden (f32->bf16) + 4 weights ----------------
__global__ void cast_all(const float* __restrict__ hidden,
                         const float* __restrict__ wq, const float* __restrict__ wk,
                         const float* __restrict__ wv, const float* __restrict__ wo,
                         bf16_t* __restrict__ hOut, bf16_t* __restrict__ wOut) {
  int blk = blockIdx.x;
  const float* src;
  bf16_t* dst;
  int i;
  if (blk < 8192) {
    src = hidden; dst = hOut;
    i = blk * 256 + threadIdx.x;
  } else {
    int w = (blk - 8192) >> 12;
    const float* srcs[4] = {wq, wk, wv, wo};
    src = srcs[w];
    dst = wOut + (size_t)w * (HID * HID);
    i = ((blk - 8192) & 4095) * 256 + threadIdx.x;
  }
  float4 v = ((const float4*)src)[i];
  bf16x4_t b;
  b[0] = (bf16_t)v.x; b[1] = (bf16_t)v.y; b[2] = (bf16_t)v.z; b[3] = (bf16_t)v.w;
  ((bf16x4_t*)dst)[i] = b;
}

// ---------------- 256x256 8-phase GEMM + fused RoPE epilogue (QK projection) -------
__global__ __launch_bounds__(512, 2) void gemm256_rope(
    const bf16_t* __restrict__ A, const bf16_t* __restrict__ Bw,
    bf16_t* __restrict__ Cb, const float* __restrict__ cosT,
    const float* __restrict__ sinT, int M, int N, int K) {
  __shared__ char smem[131072];
  const int tid = threadIdx.x, lane = tid & 63, wid = tid >> 6;
  const int wr = wid >> 2, wc = wid & 3;
  const int lr = lane & 15, lg = lane >> 4;
  const int xcd = blockIdx.x & 7, l = blockIdx.x >> 3;
  const int brow = (xcd >> 2) * 8 + (l >> 2);
  const int bcol = (xcd & 3) * 4 + (l & 3);
  const int NT = K >> 6;

  const bf16_t* Ab = A + (size_t)(brow * 256) * K;
  const bf16_t* Bb = Bw + (size_t)(bcol * 256) * K;

  f32x4 acc[8][4] = {};
  bf16x8 af[4], bfr[4];
  const int swz = (lg ^ ((lr >> 1) & 3)) << 4;

#define STAGE_HALF(t_, op, kh)                                                        \
  {                                                                                   \
    int tt = (t_) < NT ? (t_) : NT - 1;                                               \
    const bf16_t* gsrc = (op) ? Bb : Ab;                                              \
    char* ldst = smem + (tt & 1) * 65536 + (op) * 32768 + (kh) * 16384;               \
    _Pragma("unroll") for (int is = 0; is < 2; ++is) {                                \
      int p = tid + is * 512;                                                         \
      int row = p >> 2, ch = p & 3;                                                   \
      GLOAD_LDS(gsrc + (size_t)row * K + tt * 64 + (kh) * 32 +                        \
                    ((ch ^ ((row >> 1) & 3)) * 8),                                    \
                ldst + p * 16);                                                       \
    }                                                                                 \
  }

#define PHASE(cb, kh, mh, LOADB, STAGECALL, VM)                                       \
  {                                                                                   \
    _Pragma("unroll") for (int mf = 0; mf < 4; ++mf) {                                \
      int row = wr * 128 + (mh) * 64 + mf * 16 + lr;                                  \
      af[mf] = *(const bf16x8*)(smem + (cb) * 65536 + (kh) * 16384 + row * 64 + swz); \
    }                                                                                 \
    if (LOADB) {                                                                      \
      _Pragma("unroll") for (int nf = 0; nf < 4; ++nf) {                              \
        int row = wc * 64 + nf * 16 + lr;                                             \
        bfr[nf] = *(const bf16x8*)(smem + (cb) * 65536 + 32768 + (kh) * 16384 +       \
                                   row * 64 + swz);                                   \
      }                                                                               \
    }                                                                                 \
    STAGECALL;                                                                        \
    __builtin_amdgcn_s_barrier();                                                     \
    asm volatile("s_waitcnt lgkmcnt(0)" ::: "memory");                                \
    __builtin_amdgcn_sched_barrier(0);                                                \
    __builtin_amdgcn_s_setprio(1);                                                    \
    _Pragma("unroll") for (int mf = 0; mf < 4; ++mf)                                  \
      _Pragma("unroll") for (int nf = 0; nf < 4; ++nf)                                \
        acc[(mh) * 4 + mf][nf] = MFMA16(af[mf], bfr[nf], acc[(mh) * 4 + mf][nf]);     \
    __builtin_amdgcn_s_setprio(0);                                                    \
    if (VM) { asm volatile("s_waitcnt vmcnt(6)" ::: "memory"); }                      \
    __builtin_amdgcn_s_barrier();                                                     \
    __builtin_amdgcn_sched_barrier(0);                                                \
  }

  STAGE_HALF(0, 1, 0); STAGE_HALF(0, 0, 0); STAGE_HALF(0, 1, 1); STAGE_HALF(0, 0, 1);
  STAGE_HALF(1, 1, 0); STAGE_HALF(1, 0, 0); STAGE_HALF(1, 1, 1);
  asm volatile("s_waitcnt vmcnt(6)" ::: "memory");
  __builtin_amdgcn_s_barrier();
  __builtin_amdgcn_sched_barrier(0);

  const int NI = NT >> 1;
  for (int i = 0; i < NI; ++i) {
    const int t2 = 2 * i;
    PHASE(0, 0, 0, 1, STAGE_HALF(t2 + 1, 0, 1), 0);
    PHASE(0, 0, 1, 0, STAGE_HALF(t2 + 2, 1, 0), 0);
    PHASE(0, 1, 0, 1, STAGE_HALF(t2 + 2, 0, 0), 0);
    PHASE(0, 1, 1, 0, STAGE_HALF(t2 + 2, 1, 1), 1);
    PHASE(1, 0, 0, 1, STAGE_HALF(t2 + 2, 0, 1), 0);
    PHASE(1, 0, 1, 0, STAGE_HALF(t2 + 3, 1, 0), 0);
    PHASE(1, 1, 0, 1, STAGE_HALF(t2 + 3, 0, 0), 0);
    PHASE(1, 1, 1, 0, STAGE_HALF(t2 + 3, 1, 1), 1);
  }
#undef PHASE
#undef STAGE_HALF

  // ---- fused RoPE epilogue ----
  asm volatile("s_waitcnt vmcnt(0)" ::: "memory");
  __builtin_amdgcn_s_barrier();

  const int base = wid * 16384;
#pragma unroll
  for (int mi = 0; mi < 8; ++mi)
#pragma unroll
    for (int nf = 0; nf < 4; ++nf)
#pragma unroll
      for (int r = 0; r < 4; ++r)
        *(bf16_t*)(smem + base + ((mi * 4 + nf) * 4 + r) * 128 + lane * 2) =
            (bf16_t)acc[mi][nf][r];
  __syncthreads();

  const int pbase = (wid ^ 1) * 16384;
  const float SCALE = 0.12751569978848444f;  // log2(e)/sqrt(128) for Q columns
#pragma unroll
  for (int mi = 0; mi < 8; ++mi)
#pragma unroll
    for (int nf = 0; nf < 4; ++nf) {
      int col = bcol * 256 + wc * 64 + nf * 16 + lr;
      int d = col & 127;
      const float sc = (col < 2048) ? SCALE : 1.0f;
#pragma unroll
      for (int r = 0; r < 4; ++r) {
        int row = brow * 256 + wr * 128 + (mi >> 2) * 64 + (mi & 3) * 16 + lg * 4 + r;
        int s = row & (SEQ - 1);
        float part = (float)*(const bf16_t*)(smem + pbase +
                                             ((mi * 4 + nf) * 4 + r) * 128 + lane * 2);
        float cc = cosT[s * HDIM + d];
        float ss = sinT[s * HDIM + d];
        float own = acc[mi][nf][r];
        float ov = (d < 64) ? (own * cc - part * ss) : (own * cc + part * ss);
        Cb[(size_t)row * N + col] = (bf16_t)(ov * sc);
      }
    }
}

// ---------------- V GEMM + fused transpose epilogue: writes Vt[b][h][d][s] ---------
__global__ __launch_bounds__(256, 3) void gemm_v(
    const bf16_t* __restrict__ A, const bf16_t* __restrict__ Bw,
    bf16_t* __restrict__ Vt, int M, int N, int K) {
  __shared__ char smv[34816];
  bf16_t* As = (bf16_t*)smv;
  bf16_t* Bs = (bf16_t*)(smv + 16384);
  const int tid = threadIdx.x;
  const int lane = tid & 63, wid = tid >> 6;
  const int wr = wid >> 1, wc = wid & 1;
  const int lr = lane & 15, lg = lane >> 4;
  const int nwg = gridDim.x;
  const int lid = (blockIdx.x & 7) * (nwg >> 3) + (blockIdx.x >> 3);
  const int nbc = N >> 7;
  const int brow = lid / nbc, bcol = lid % nbc;

  f32x4 acc[4][4] = {};
  const int swz = lg ^ ((lr >> 1) & 3);

  const int srow = tid >> 2, sch = tid & 3;
#define GSTAGE(k0, bb)                                                                   \
  {                                                                                      \
    _Pragma("unroll") for (int is = 0; is < 2; ++is) {                                   \
      int row = srow + is * 64;                                                          \
      int g = (sch ^ ((row >> 1) & 3)) * 8;                                              \
      GLOAD_LDS(A + (size_t)(brow * 128 + row) * K + (k0) + g,                           \
                As + (bb) * 4096 + (row * 4 + sch) * 8);                                 \
      GLOAD_LDS(Bw + (size_t)(bcol * 128 + row) * K + (k0) + g,                          \
                Bs + (bb) * 4096 + (row * 4 + sch) * 8);                                 \
    }                                                                                    \
  }

  GSTAGE(0, 0);
  __syncthreads();

  const int nt = K / 32;
  for (int t = 0; t < nt; ++t) {
    const int cb = t & 1;
    if (t + 1 < nt) GSTAGE((t + 1) * 32, cb ^ 1);
    bf16x8 af[4], bfr[4];
#pragma unroll
    for (int m = 0; m < 4; ++m)
      af[m] = *(const bf16x8*)(As + cb * 4096 + (wr * 64 + m * 16 + lr) * 32 + swz * 8);
#pragma unroll
    for (int n = 0; n < 4; ++n)
      bfr[n] = *(const bf16x8*)(Bs + cb * 4096 + (wc * 64 + n * 16 + lr) * 32 + swz * 8);
#pragma unroll
    for (int m = 0; m < 4; ++m)
#pragma unroll
      for (int n = 0; n < 4; ++n)
        acc[m][n] = MFMA16(af[m], bfr[n], acc[m][n]);
    __syncthreads();
  }
#undef GSTAGE

  // ---- fused transpose epilogue ----
  bf16_t* tr = (bf16_t*)smv;                   // [128 d][136 s-capacity]
#pragma unroll
  for (int m = 0; m < 4; ++m)
#pragma unroll
    for (int n = 0; n < 4; ++n) {
      int d = wc * 64 + n * 16 + lr;
#pragma unroll
      for (int r = 0; r < 4; ++r) {
        int s = wr * 64 + m * 16 + lg * 4 + r;
        tr[d * 136 + s] = (bf16_t)acc[m][n][r];
      }
    }
  __syncthreads();

  const int b = brow >> 4, h = bcol;
  const int s0 = (brow & 15) * 128;
  bf16_t* vbase = Vt + ((size_t)(b * NHEAD + h) * HDIM) * SEQ + s0;
  const int dd = (lane >> 3);
  const int sl = (lane & 7) * 8;
#pragma unroll
  for (int it = 0; it < 4; ++it) {
    int d = wid * 32 + it * 8 + dd;
#pragma unroll
    for (int si = 0; si < 2; ++si) {
      int s = si * 64 + sl;
      bf16x8 v = *(const bf16x8*)(tr + d * 136 + s);
      *(bf16x8*)(vbase + (size_t)d * SEQ + s) = v;
    }
  }
}

// ---------------- GEMM: C = A * B^T, 2-phase double-buffered (128x128) -------------
__global__ __launch_bounds__(256, 3) void gemm_bt(
    const bf16_t* __restrict__ A, const bf16_t* __restrict__ Bw,
    bf16_t* __restrict__ Cb, float* __restrict__ Cf,
    int M, int N, int K) {
  __shared__ bf16_t As[2][128 * 32];
  __shared__ bf16_t Bs[2][128 * 32];
  const int tid = threadIdx.x;
  const int lane = tid & 63, wid = tid >> 6;
  const int wr = wid >> 1, wc = wid & 1;
  const int lr = lane & 15, lg = lane >> 4;
  const int nwg = gridDim.x;
  const int lid = (blockIdx.x & 7) * (nwg >> 3) + (blockIdx.x >> 3);
  const int nbc = N >> 7;
  const int brow = lid / nbc, bcol = lid % nbc;

  f32x4 acc[4][4] = {};
  const int swz = lg ^ ((lr >> 1) & 3);

  const int srow = tid >> 2, sch = tid & 3;
#define GSTAGE(k0, bb)                                                                   \
  {                                                                                      \
    _Pragma("unroll") for (int is = 0; is < 2; ++is) {                                   \
      int row = srow + is * 64;                                                          \
      int g = (sch ^ ((row >> 1) & 3)) * 8;                                              \
      GLOAD_LDS(A + (size_t)(brow * 128 + row) * K + (k0) + g,                           \
                &As[bb][(row * 4 + sch) * 8]);                                           \
      GLOAD_LDS(Bw + (size_t)(bcol * 128 + row) * K + (k0) + g,                          \
                &Bs[bb][(row * 4 + sch) * 8]);                                           \
    }                                                                                    \
  }

  GSTAGE(0, 0);
  __syncthreads();

  const int nt = K / 32;
  for (int t = 0; t < nt; ++t) {
    const int cb = t & 1;
    if (t + 1 < nt) GSTAGE((t + 1) * 32, cb ^ 1);
    bf16x8 af[4], bfr[4];
#pragma unroll
    for (int m = 0; m < 4; ++m)
      af[m] = *(const bf16x8*)(&As[cb][(wr * 64 + m * 16 + lr) * 32 + swz * 8]);
#pragma unroll
    for (int n = 0; n < 4; ++n)
      bfr[n] = *(const bf16x8*)(&Bs[cb][(wc * 64 + n * 16 + lr) * 32 + swz * 8]);
#pragma unroll
    for (int m = 0; m < 4; ++m)
#pragma unroll
      for (int n = 0; n < 4; ++n)
        acc[m][n] = MFMA16(af[m], bfr[n], acc[m][n]);
    __syncthreads();
  }
#undef GSTAGE

#pragma unroll
  for (int m = 0; m < 4; ++m)
#pragma unroll
    for (int n = 0; n < 4; ++n)
#pragma unroll
      for (int r = 0; r < 4; ++r) {
        int row = brow * 128 + wr * 64 + m * 16 + lg * 4 + r;
        int col = bcol * 128 + wc * 64 + n * 16 + lr;
        float v = acc[m][n][r];
        if (Cf) Cf[(size_t)row * N + col] = v;
        else    Cb[(size_t)row * N + col] = (bf16_t)v;
      }
}

// ---------------- mask pack: mask f32 -> maskP[b][kg][q][kl'] bf16, x log2e ---------
__global__ void mask_pack(const float* __restrict__ m, bf16_t* __restrict__ mp) {
  const float L2E = 1.4426950408889634f;
  __shared__ float t[32][33];
  int tx = threadIdx.x & 31, ty = threadIdx.x >> 5;
  int q0 = blockIdx.x * 32, k0 = blockIdx.y * 32;
  const float* mb = m + (size_t)blockIdx.z * SEQ * SEQ;
#pragma unroll
  for (int j = 0; j < 4; ++j)
    t[ty + j * 8][tx] = mb[(size_t)(q0 + ty + j * 8) * SEQ + k0 + tx];
  __syncthreads();
  int r = tx & 15, hi = tx >> 4;
  int kl = (r & 3) + 8 * (r >> 2) + 4 * hi;
  bf16_t* ob = mp + ((size_t)(blockIdx.z * 64 + blockIdx.y) * 2048 + q0) * 32;
#pragma unroll
  for (int j = 0; j < 4; ++j) {
    int qloc = ty + j * 8;
    ob[(size_t)qloc * 32 + tx] = (bf16_t)(t[qloc][kl] * L2E);
  }
}

// ---------------- flash attention fwd v7 (R13/R15-verified, best-known) -------------
// Per-kb pipeline (QK chain of kb+1 before softmax of kb), permlane pack, exp2-folded
// softmax, setprio around MFMA clusters. Conflict-free (row&15) XOR LDS.
__global__ __launch_bounds__(512, 2) void flash_fwd(
    const bf16_t* __restrict__ Qf, const bf16_t* __restrict__ Kf,
    const bf16_t* __restrict__ Vt, const bf16_t* __restrict__ maskP,
    bf16_t* __restrict__ AO) {
  __shared__ char smem[131072];          // K 2x32K | V 2x32K
  char* KsB = smem;
  char* VsB = smem + 65536;
  const int tid = threadIdx.x, lane = tid & 63, wid = tid >> 6;
  const int q32 = lane & 31, hi = lane >> 5;

  const int x = blockIdx.x;
  const int bh = x & 31, qt = x >> 5;          // qt 0..7
  const int b = bh >> 4, h = bh & 15;
  const int qg = qt * 256 + wid * 32 + q32;

  bf16x8 qf[8];
  const bf16_t* qptr = Qf + (size_t)(b * SEQ + qg) * LDK + h * HDIM + hi * 8;
#pragma unroll
  for (int ds = 0; ds < 8; ++ds) qf[ds] = *(const bf16x8*)(qptr + ds * 16);

  const bf16_t* mQ = maskP + (size_t)b * 64 * 65536 + (size_t)qg * 32 + hi * 16;

  float mrun = -INFINITY, lpart = 0.f;
  f32x16 o[4] = {};
  const int lswz = (q32 & 15) << 4;

#define STAGE_KV(kt_, bb)                                                                \
  {                                                                                      \
    const int kb0_ = (kt_) * 128;                                                        \
    _Pragma("unroll") for (int is = 0; is < 4; ++is) {                                   \
      int p = tid + is * 512;                                                            \
      int row = p >> 4, ch = p & 15;                                                     \
      int src = (ch * 16) ^ ((row & 15) << 4);                                           \
      GLOAD_LDS((const char*)(Kf + (size_t)(b * SEQ + kb0_ + row) * LDK + h * HDIM) +    \
                    src,                                                                 \
                KsB + (bb) * 32768 + p * 16);                                            \
      GLOAD_LDS((const char*)(Vt + (size_t)(bh * HDIM + row) * SEQ + kb0_) + src,        \
                VsB + (bb) * 32768 + p * 16);                                            \
    }                                                                                    \
  }

#define INIT_SACC(kb)                                                                    \
  {                                                                                      \
    _Pragma("unroll") for (int r = 0; r < 8; ++r) {                                      \
      sacc[kb][r]     = (float)mk[2 * (kb)][r];                                          \
      sacc[kb][8 + r] = (float)mk[2 * (kb) + 1][r];                                      \
    }                                                                                    \
  }
#define QK_CHAIN(kb)                                                                     \
  {                                                                                      \
    const char* Kb_ = KsB + cur * 32768 + q32 * 256 + (kb) * 8192;                       \
    __builtin_amdgcn_s_setprio(1);                                                       \
    _Pragma("unroll") for (int ds = 0; ds < 8; ++ds) {                                   \
      bf16x8 kfr = *(const bf16x8*)(Kb_ + ((ds * 32 + hi * 16) ^ lswz));                 \
      sacc[kb] = MFMA32(kfr, qf[ds], sacc[kb]);                                          \
    }                                                                                    \
    __builtin_amdgcn_s_setprio(0);                                                       \
  }

  STAGE_KV(0, 0);
  __syncthreads();

  const int NT = SEQ / 128;                     // 16
  for (int kt = 0; kt < NT; ++kt) {
    const int cur = kt & 1;
    if (kt + 1 < NT) STAGE_KV(kt + 1, cur ^ 1);

    bf16x8 mk[8];
#pragma unroll
    for (int kb = 0; kb < 4; ++kb) {
      const size_t mo = (size_t)(kt * 4 + kb) * 65536;
      mk[2 * kb]     = *(const bf16x8*)(mQ + mo);
      mk[2 * kb + 1] = *(const bf16x8*)(mQ + mo + 8);
    }

    f32x16 sacc[4];
    INIT_SACC(0);
    QK_CHAIN(0);

#pragma unroll
    for (int kb = 0; kb < 4; ++kb) {
      if (kb < 3) {
        INIT_SACC(kb + 1);
        QK_CHAIN(kb + 1);
      }

      float a0 = fmaxf(fmaxf(sacc[kb][0], sacc[kb][1]), fmaxf(sacc[kb][2], sacc[kb][3]));
      float a1 = fmaxf(fmaxf(sacc[kb][4], sacc[kb][5]), fmaxf(sacc[kb][6], sacc[kb][7]));
      float a2 = fmaxf(fmaxf(sacc[kb][8], sacc[kb][9]), fmaxf(sacc[kb][10], sacc[kb][11]));
      float a3 = fmaxf(fmaxf(sacc[kb][12], sacc[kb][13]),
                       fmaxf(sacc[kb][14], sacc[kb][15]));
      float mx = fmaxf(fmaxf(a0, a1), fmaxf(a2, a3));
      mx = fmaxf(mx, __shfl_xor(mx, 32, 64));
      if (!__all(mx <= mrun + 11.5f)) {          // e^8-equivalent bound in base-2
        float mnew = fmaxf(mrun, mx);
        float corr = exp2_fast(mrun - mnew);
        mrun = mnew; lpart *= corr;
#pragma unroll
        for (int d0 = 0; d0 < 4; ++d0)
#pragma unroll
          for (int r = 0; r < 16; ++r) o[d0][r] *= corr;
      }

      float p_[16];
#pragma unroll
      for (int r = 0; r < 16; ++r) p_[r] = exp2_fast(sacc[kb][r] - mrun);
      {
        float t0 = (p_[0] + p_[1]) + (p_[2] + p_[3]);
        float t1 = (p_[4] + p_[5]) + (p_[6] + p_[7]);
        float t2 = (p_[8] + p_[9]) + (p_[10] + p_[11]);
        float t3 = (p_[12] + p_[13]) + (p_[14] + p_[15]);
        lpart += (t0 + t1) + (t2 + t3);
      }

      const char* Vbase = VsB + cur * 32768 + q32 * 256;
#pragma unroll
      for (int s = 0; s < 2; ++s) {
        bf16x8 pav = pack_slice(p_ + 8 * s);
        const int gs = kb * 2 + s;
        __builtin_amdgcn_s_setprio(1);
#pragma unroll
        for (int d0 = 0; d0 < 4; ++d0) {
          bf16x8 vf = *(const bf16x8*)(Vbase + d0 * 8192 +
                                       ((gs * 32 + hi * 16) ^ lswz));
          o[d0] = MFMA32(vf, pav, o[d0]);
        }
        __builtin_amdgcn_s_setprio(0);
      }
    }
    __syncthreads();
  }
#undef STAGE_KV
#undef INIT_SACC
#undef QK_CHAIN

  float l = lpart + __shfl_xor(lpart, 32, 64);
  float rl = 1.f / l;
  bf16_t* aorow = AO + (size_t)(b * SEQ + qg) * HID + h * HDIM;
#pragma unroll
  for (int d0 = 0; d0 < 4; ++d0)
#pragma unroll
    for (int g = 0; g < 4; ++g) {
      unsigned lo = pk2(o[d0][4 * g + 0] * rl, o[d0][4 * g + 1] * rl);
      unsigned hi2 = pk2(o[d0][4 * g + 2] * rl, o[d0][4 * g + 3] * rl);
      int d = d0 * 32 + 8 * g + 4 * hi;
      *(unsigned*)(aorow + d) = lo;
      *(unsigned*)(aorow + d + 2) = hi2;
    }
}

// ---------------- launch ----------------
extern "C" void kernel_launch(void* const* d_in, const int* in_sizes, int n_in,
                              void* d_out, int out_size, void* d_ws, size_t ws_size,
                              hipStream_t stream) {
  const float* hidden = (const float*)d_in[0];
  const float* cost   = (const float*)d_in[1];
  const float* sint   = (const float*)d_in[2];
  const float* mask   = (const float*)d_in[3];
  const float* Wq     = (const float*)d_in[4];
  const float* Wk     = (const float*)d_in[5];
  const float* Wv     = (const float*)d_in[6];
  const float* Wo     = (const float*)d_in[7];
  float* out = (float*)d_out;
  char* ws = (char*)d_ws;

  bf16_t* Af    = (bf16_t*)(ws + 0);
  bf16_t* Wqb   = (bf16_t*)(ws + 16777216);
  bf16_t* Wvb   = (bf16_t*)(ws + 33554432);
  bf16_t* Wob   = (bf16_t*)(ws + 41943040);
  bf16_t* QK    = (bf16_t*)(ws + 50331648);
  bf16_t* maskP = (bf16_t*)(ws + 83886080);
  bf16_t* Vt    = (bf16_t*)(ws + 100663296);
  bf16_t* AO    = (bf16_t*)(ws + 16777216);

  cast_all<<<24576, 256, 0, stream>>>(hidden, Wq, Wk, Wv, Wo, Af, Wqb);

  gemm256_rope<<<256, 512, 0, stream>>>(Af, Wqb, QK, cost, sint, 4096, LDK, HID);
  gemm_v<<<512, 256, 0, stream>>>(Af, Wvb, Vt, 4096, HID, HID);

  mask_pack<<<dim3(64, 64, 2), 256, 0, stream>>>(mask, maskP);

  flash_fwd<<<256, 512, 0, stream>>>(QK, QK + 2048, Vt, maskP, AO);

  gemm_bt<<<512, 256, 0, stream>>>(AO, Wob, nullptr, out, 4096, HID, HID);
}

// Round 19
// 292.083 us; speedup vs baseline: 1.0120x; 1.0018x over previous
//
#include <hip/hip_runtime.h>
#include <hip/hip_bf16.h>
#include <math.h>

// B=2, S=2048, H=2048, NH=16, HD=128
#define SEQ 2048
#define HID 2048
#define NHEAD 16
#define HDIM 128
#define LDK 4096   // fused QK row stride

typedef __bf16 bf16_t;
typedef __bf16 bf16x2 __attribute__((ext_vector_type(2)));
typedef __bf16 bf16x4_t __attribute__((ext_vector_type(4)));
typedef __bf16 bf16x8 __attribute__((ext_vector_type(8)));
typedef float f32x4 __attribute__((ext_vector_type(4)));
typedef float f32x16 __attribute__((ext_vector_type(16)));
typedef unsigned u32x4 __attribute__((ext_vector_type(4)));

#define MFMA16(a, b, c) __builtin_amdgcn_mfma_f32_16x16x32_bf16(a, b, c, 0, 0, 0)
#define MFMA32(a, b, c) __builtin_amdgcn_mfma_f32_32x32x16_bf16(a, b, c, 0, 0, 0)
#define GLOAD_LDS(g, l) \
  __builtin_amdgcn_global_load_lds((const __attribute__((address_space(1))) void*)(g), \
                                   (__attribute__((address_space(3))) void*)(l), 16, 0, 0)

static __device__ inline unsigned pk2(float lo, float hi) {
  bf16x2 t; t[0] = (bf16_t)lo; t[1] = (bf16_t)hi;
  return __builtin_bit_cast(unsigned, t);
}

// native 2^x (v_exp_f32 computes exp2); avoids glibc __exp2f macro collision
static __device__ inline float exp2_fast(float x) {
  float r;
  asm("v_exp_f32 %0, %1" : "=v"(r) : "v"(x));
  return r;
}

// pack 8 p-values into the PV B-fragment via v_permlane32_swap (verified R13).
// Safe because the two operands hold DIFFERENT values and both outputs are used.
static __device__ inline bf16x8 pack_slice(const float* p) {
  unsigned A1 = pk2(p[0], p[1]);
  unsigned A2 = pk2(p[2], p[3]);
  unsigned B1 = pk2(p[4], p[5]);
  unsigned B2 = pk2(p[6], p[7]);
  asm("v_permlane32_swap_b32 %0, %1" : "+v"(A1), "+v"(B1));
  asm("v_permlane32_swap_b32 %0, %1" : "+v"(A2), "+v"(B2));
  u32x4 W = {A1, A2, B1, B2};
  return __builtin_bit_cast(bf16x8, W);
}

// ---------------- merged cast kernel: hidden (f32->bf16) + 4 weights ----------------
__global__ void cast_all(const float* __restrict__ hidden,
                         const float* __restrict__ wq, const float* __restrict__ wk,
                         const float* __restrict__ wv, const float* __restrict__ wo,
                         bf16_t* __restrict__ hOut, bf16_t* __restrict__ wOut) {
  int blk = blockIdx.x;
  const float* src;
  bf16_t* dst;
  int i;
  if (blk < 8192) {
    src = hidden; dst = hOut;
    i = blk * 256 + threadIdx.x;
  } else {
    int w = (blk - 8192) >> 12;
    const float* srcs[4] = {wq, wk, wv, wo};
    src = srcs[w];
    dst = wOut + (size_t)w * (HID * HID);
    i = ((blk - 8192) & 4095) * 256 + threadIdx.x;
  }
  float4 v = ((const float4*)src)[i];
  bf16x4_t b;
  b[0] = (bf16_t)v.x; b[1] = (bf16_t)v.y; b[2] = (bf16_t)v.z; b[3] = (bf16_t)v.w;
  ((bf16x4_t*)dst)[i] = b;
}

// ---------------- 256x256 8-phase GEMM + fused RoPE epilogue (QK projection) -------
__global__ __launch_bounds__(512, 2) void gemm256_rope(
    const bf16_t* __restrict__ A, const bf16_t* __restrict__ Bw,
    bf16_t* __restrict__ Cb, const float* __restrict__ cosT,
    const float* __restrict__ sinT, int M, int N, int K) {
  __shared__ char smem[131072];
  const int tid = threadIdx.x, lane = tid & 63, wid = tid >> 6;
  const int wr = wid >> 2, wc = wid & 3;
  const int lr = lane & 15, lg = lane >> 4;
  const int xcd = blockIdx.x & 7, l = blockIdx.x >> 3;
  const int brow = (xcd >> 2) * 8 + (l >> 2);
  const int bcol = (xcd & 3) * 4 + (l & 3);
  const int NT = K >> 6;

  const bf16_t* Ab = A + (size_t)(brow * 256) * K;
  const bf16_t* Bb = Bw + (size_t)(bcol * 256) * K;

  f32x4 acc[8][4] = {};
  bf16x8 af[4], bfr[4];
  const int swz = (lg ^ ((lr >> 1) & 3)) << 4;

#define STAGE_HALF(t_, op, kh)                                                        \
  {                                                                                   \
    int tt = (t_) < NT ? (t_) : NT - 1;                                               \
    const bf16_t* gsrc = (op) ? Bb : Ab;                                              \
    char* ldst = smem + (tt & 1) * 65536 + (op) * 32768 + (kh) * 16384;               \
    _Pragma("unroll") for (int is = 0; is < 2; ++is) {                                \
      int p = tid + is * 512;                                                         \
      int row = p >> 2, ch = p & 3;                                                   \
      GLOAD_LDS(gsrc + (size_t)row * K + tt * 64 + (kh) * 32 +                        \
                    ((ch ^ ((row >> 1) & 3)) * 8),                                    \
                ldst + p * 16);                                                       \
    }                                                                                 \
  }

#define PHASE(cb, kh, mh, LOADB, STAGECALL, VM)                                       \
  {                                                                                   \
    _Pragma("unroll") for (int mf = 0; mf < 4; ++mf) {                                \
      int row = wr * 128 + (mh) * 64 + mf * 16 + lr;                                  \
      af[mf] = *(const bf16x8*)(smem + (cb) * 65536 + (kh) * 16384 + row * 64 + swz); \
    }                                                                                 \
    if (LOADB) {                                                                      \
      _Pragma("unroll") for (int nf = 0; nf < 4; ++nf) {                              \
        int row = wc * 64 + nf * 16 + lr;                                             \
        bfr[nf] = *(const bf16x8*)(smem + (cb) * 65536 + 32768 + (kh) * 16384 +       \
                                   row * 64 + swz);                                   \
      }                                                                               \
    }                                                                                 \
    STAGECALL;                                                                        \
    __builtin_amdgcn_s_barrier();                                                     \
    asm volatile("s_waitcnt lgkmcnt(0)" ::: "memory");                                \
    __builtin_amdgcn_sched_barrier(0);                                                \
    __builtin_amdgcn_s_setprio(1);                                                    \
    _Pragma("unroll") for (int mf = 0; mf < 4; ++mf)                                  \
      _Pragma("unroll") for (int nf = 0; nf < 4; ++nf)                                \
        acc[(mh) * 4 + mf][nf] = MFMA16(af[mf], bfr[nf], acc[(mh) * 4 + mf][nf]);     \
    __builtin_amdgcn_s_setprio(0);                                                    \
    if (VM) { asm volatile("s_waitcnt vmcnt(6)" ::: "memory"); }                      \
    __builtin_amdgcn_s_barrier();                                                     \
    __builtin_amdgcn_sched_barrier(0);                                                \
  }

  STAGE_HALF(0, 1, 0); STAGE_HALF(0, 0, 0); STAGE_HALF(0, 1, 1); STAGE_HALF(0, 0, 1);
  STAGE_HALF(1, 1, 0); STAGE_HALF(1, 0, 0); STAGE_HALF(1, 1, 1);
  asm volatile("s_waitcnt vmcnt(6)" ::: "memory");
  __builtin_amdgcn_s_barrier();
  __builtin_amdgcn_sched_barrier(0);

  const int NI = NT >> 1;
  for (int i = 0; i < NI; ++i) {
    const int t2 = 2 * i;
    PHASE(0, 0, 0, 1, STAGE_HALF(t2 + 1, 0, 1), 0);
    PHASE(0, 0, 1, 0, STAGE_HALF(t2 + 2, 1, 0), 0);
    PHASE(0, 1, 0, 1, STAGE_HALF(t2 + 2, 0, 0), 0);
    PHASE(0, 1, 1, 0, STAGE_HALF(t2 + 2, 1, 1), 1);
    PHASE(1, 0, 0, 1, STAGE_HALF(t2 + 2, 0, 1), 0);
    PHASE(1, 0, 1, 0, STAGE_HALF(t2 + 3, 1, 0), 0);
    PHASE(1, 1, 0, 1, STAGE_HALF(t2 + 3, 0, 0), 0);
    PHASE(1, 1, 1, 0, STAGE_HALF(t2 + 3, 1, 1), 1);
  }
#undef PHASE
#undef STAGE_HALF

  // ---- fused RoPE epilogue ----
  asm volatile("s_waitcnt vmcnt(0)" ::: "memory");
  __builtin_amdgcn_s_barrier();

  const int base = wid * 16384;
#pragma unroll
  for (int mi = 0; mi < 8; ++mi)
#pragma unroll
    for (int nf = 0; nf < 4; ++nf)
#pragma unroll
      for (int r = 0; r < 4; ++r)
        *(bf16_t*)(smem + base + ((mi * 4 + nf) * 4 + r) * 128 + lane * 2) =
            (bf16_t)acc[mi][nf][r];
  __syncthreads();

  const int pbase = (wid ^ 1) * 16384;
  const float SCALE = 0.12751569978848444f;  // log2(e)/sqrt(128) for Q columns
#pragma unroll
  for (int mi = 0; mi < 8; ++mi)
#pragma unroll
    for (int nf = 0; nf < 4; ++nf) {
      int col = bcol * 256 + wc * 64 + nf * 16 + lr;
      int d = col & 127;
      const float sc = (col < 2048) ? SCALE : 1.0f;
#pragma unroll
      for (int r = 0; r < 4; ++r) {
        int row = brow * 256 + wr * 128 + (mi >> 2) * 64 + (mi & 3) * 16 + lg * 4 + r;
        int s = row & (SEQ - 1);
        float part = (float)*(const bf16_t*)(smem + pbase +
                                             ((mi * 4 + nf) * 4 + r) * 128 + lane * 2);
        float cc = cosT[s * HDIM + d];
        float ss = sinT[s * HDIM + d];
        float own = acc[mi][nf][r];
        float ov = (d < 64) ? (own * cc - part * ss) : (own * cc + part * ss);
        Cb[(size_t)row * N + col] = (bf16_t)(ov * sc);
      }
    }
}

// ---------------- V GEMM + fused transpose epilogue: writes Vt[b][h][d][s] ---------
__global__ __launch_bounds__(256, 3) void gemm_v(
    const bf16_t* __restrict__ A, const bf16_t* __restrict__ Bw,
    bf16_t* __restrict__ Vt, int M, int N, int K) {
  __shared__ char smv[34816];
  bf16_t* As = (bf16_t*)smv;
  bf16_t* Bs = (bf16_t*)(smv + 16384);
  const int tid = threadIdx.x;
  const int lane = tid & 63, wid = tid >> 6;
  const int wr = wid >> 1, wc = wid & 1;
  const int lr = lane & 15, lg = lane >> 4;
  const int nwg = gridDim.x;
  const int lid = (blockIdx.x & 7) * (nwg >> 3) + (blockIdx.x >> 3);
  const int nbc = N >> 7;
  const int brow = lid / nbc, bcol = lid % nbc;

  f32x4 acc[4][4] = {};
  const int swz = lg ^ ((lr >> 1) & 3);

  const int srow = tid >> 2, sch = tid & 3;
#define GSTAGE(k0, bb)                                                                   \
  {                                                                                      \
    _Pragma("unroll") for (int is = 0; is < 2; ++is) {                                   \
      int row = srow + is * 64;                                                          \
      int g = (sch ^ ((row >> 1) & 3)) * 8;                                              \
      GLOAD_LDS(A + (size_t)(brow * 128 + row) * K + (k0) + g,                           \
                As + (bb) * 4096 + (row * 4 + sch) * 8);                                 \
      GLOAD_LDS(Bw + (size_t)(bcol * 128 + row) * K + (k0) + g,                          \
                Bs + (bb) * 4096 + (row * 4 + sch) * 8);                                 \
    }                                                                                    \
  }

  GSTAGE(0, 0);
  __syncthreads();

  const int nt = K / 32;
  for (int t = 0; t < nt; ++t) {
    const int cb = t & 1;
    if (t + 1 < nt) GSTAGE((t + 1) * 32, cb ^ 1);
    bf16x8 af[4], bfr[4];
#pragma unroll
    for (int m = 0; m < 4; ++m)
      af[m] = *(const bf16x8*)(As + cb * 4096 + (wr * 64 + m * 16 + lr) * 32 + swz * 8);
#pragma unroll
    for (int n = 0; n < 4; ++n)
      bfr[n] = *(const bf16x8*)(Bs + cb * 4096 + (wc * 64 + n * 16 + lr) * 32 + swz * 8);
#pragma unroll
    for (int m = 0; m < 4; ++m)
#pragma unroll
      for (int n = 0; n < 4; ++n)
        acc[m][n] = MFMA16(af[m], bfr[n], acc[m][n]);
    __syncthreads();
  }
#undef GSTAGE

  // ---- fused transpose epilogue ----
  bf16_t* tr = (bf16_t*)smv;                   // [128 d][136 s-capacity]
#pragma unroll
  for (int m = 0; m < 4; ++m)
#pragma unroll
    for (int n = 0; n < 4; ++n) {
      int d = wc * 64 + n * 16 + lr;
#pragma unroll
      for (int r = 0; r < 4; ++r) {
        int s = wr * 64 + m * 16 + lg * 4 + r;
        tr[d * 136 + s] = (bf16_t)acc[m][n][r];
      }
    }
  __syncthreads();

  const int b = brow >> 4, h = bcol;
  const int s0 = (brow & 15) * 128;
  bf16_t* vbase = Vt + ((size_t)(b * NHEAD + h) * HDIM) * SEQ + s0;
  const int dd = (lane >> 3);
  const int sl = (lane & 7) * 8;
#pragma unroll
  for (int it = 0; it < 4; ++it) {
    int d = wid * 32 + it * 8 + dd;
#pragma unroll
    for (int si = 0; si < 2; ++si) {
      int s = si * 64 + sl;
      bf16x8 v = *(const bf16x8*)(tr + d * 136 + s);
      *(bf16x8*)(vbase + (size_t)d * SEQ + s) = v;
    }
  }
}

// ---------------- GEMM: C = A * B^T, 2-phase double-buffered (128x128) -------------
__global__ __launch_bounds__(256, 3) void gemm_bt(
    const bf16_t* __restrict__ A, const bf16_t* __restrict__ Bw,
    bf16_t* __restrict__ Cb, float* __restrict__ Cf,
    int M, int N, int K) {
  __shared__ bf16_t As[2][128 * 32];
  __shared__ bf16_t Bs[2][128 * 32];
  const int tid = threadIdx.x;
  const int lane = tid & 63, wid = tid >> 6;
  const int wr = wid >> 1, wc = wid & 1;
  const int lr = lane & 15, lg = lane >> 4;
  const int nwg = gridDim.x;
  const int lid = (blockIdx.x & 7) * (nwg >> 3) + (blockIdx.x >> 3);
  const int nbc = N >> 7;
  const int brow = lid / nbc, bcol = lid % nbc;

  f32x4 acc[4][4] = {};
  const int swz = lg ^ ((lr >> 1) & 3);

  const int srow = tid >> 2, sch = tid & 3;
#define GSTAGE(k0, bb)                                                                   \
  {                                                                                      \
    _Pragma("unroll") for (int is = 0; is < 2; ++is) {                                   \
      int row = srow + is * 64;                                                          \
      int g = (sch ^ ((row >> 1) & 3)) * 8;                                              \
      GLOAD_LDS(A + (size_t)(brow * 128 + row) * K + (k0) + g,                           \
                &As[bb][(row * 4 + sch) * 8]);                                           \
      GLOAD_LDS(Bw + (size_t)(bcol * 128 + row) * K + (k0) + g,                          \
                &Bs[bb][(row * 4 + sch) * 8]);                                           \
    }                                                                                    \
  }

  GSTAGE(0, 0);
  __syncthreads();

  const int nt = K / 32;
  for (int t = 0; t < nt; ++t) {
    const int cb = t & 1;
    if (t + 1 < nt) GSTAGE((t + 1) * 32, cb ^ 1);
    bf16x8 af[4], bfr[4];
#pragma unroll
    for (int m = 0; m < 4; ++m)
      af[m] = *(const bf16x8*)(&As[cb][(wr * 64 + m * 16 + lr) * 32 + swz * 8]);
#pragma unroll
    for (int n = 0; n < 4; ++n)
      bfr[n] = *(const bf16x8*)(&Bs[cb][(wc * 64 + n * 16 + lr) * 32 + swz * 8]);
#pragma unroll
    for (int m = 0; m < 4; ++m)
#pragma unroll
      for (int n = 0; n < 4; ++n)
        acc[m][n] = MFMA16(af[m], bfr[n], acc[m][n]);
    __syncthreads();
  }
#undef GSTAGE

#pragma unroll
  for (int m = 0; m < 4; ++m)
#pragma unroll
    for (int n = 0; n < 4; ++n)
#pragma unroll
      for (int r = 0; r < 4; ++r) {
        int row = brow * 128 + wr * 64 + m * 16 + lg * 4 + r;
        int col = bcol * 128 + wc * 64 + n * 16 + lr;
        float v = acc[m][n][r];
        if (Cf) Cf[(size_t)row * N + col] = v;
        else    Cb[(size_t)row * N + col] = (bf16_t)v;
      }
}

// ---------------- mask pack: mask f32 -> maskP[b][kg][q][kl'] bf16, x log2e ---------
__global__ void mask_pack(const float* __restrict__ m, bf16_t* __restrict__ mp) {
  const float L2E = 1.4426950408889634f;
  __shared__ float t[32][33];
  int tx = threadIdx.x & 31, ty = threadIdx.x >> 5;
  int q0 = blockIdx.x * 32, k0 = blockIdx.y * 32;
  const float* mb = m + (size_t)blockIdx.z * SEQ * SEQ;
#pragma unroll
  for (int j = 0; j < 4; ++j)
    t[ty + j * 8][tx] = mb[(size_t)(q0 + ty + j * 8) * SEQ + k0 + tx];
  __syncthreads();
  int r = tx & 15, hi = tx >> 4;
  int kl = (r & 3) + 8 * (r >> 2) + 4 * hi;
  bf16_t* ob = mp + ((size_t)(blockIdx.z * 64 + blockIdx.y) * 2048 + q0) * 32;
#pragma unroll
  for (int j = 0; j < 4; ++j) {
    int qloc = ty + j * 8;
    ob[(size_t)qloc * 32 + tx] = (bf16_t)(t[qloc][kl] * L2E);
  }
}

// ---------------- flash attention fwd v9: v7 body, 2 independent blocks/CU ----------
// 4 waves x 32q = 128 q/block, KVBLK=64 double-buffered (64 KB LDS -> 2 blocks/CU:
// barrier drains of the two blocks interleave instead of stalling all 8 waves).
// K tile [64 keys][256B] with (row&15) XOR (verified); V tile pair-interleaved
// [64 rows][256B] (row r = d=2r | d=2r+1) with R9-verified stage/read formulas.
// Softmax/pack/pipeline identical to R13/R15-verified v7.
__global__ __launch_bounds__(256, 2) void flash_fwd(
    const bf16_t* __restrict__ Qf, const bf16_t* __restrict__ Kf,
    const bf16_t* __restrict__ Vt, const bf16_t* __restrict__ maskP,
    bf16_t* __restrict__ AO) {
  __shared__ char smem[65536];           // K 2x16K | V 2x16K
  char* KsB = smem;
  char* VsB = smem + 32768;
  const int tid = threadIdx.x, lane = tid & 63, wid = tid >> 6;
  const int q32 = lane & 31, hi = lane >> 5;

  const int x = blockIdx.x;
  const int bh = x & 31, qt = x >> 5;          // qt 0..15
  const int b = bh >> 4, h = bh & 15;
  const int qg = qt * 128 + wid * 32 + q32;

  bf16x8 qf[8];
  const bf16_t* qptr = Qf + (size_t)(b * SEQ + qg) * LDK + h * HDIM + hi * 8;
#pragma unroll
  for (int ds = 0; ds < 8; ++ds) qf[ds] = *(const bf16x8*)(qptr + ds * 16);

  const bf16_t* mQ = maskP + (size_t)b * 64 * 65536 + (size_t)qg * 32 + hi * 16;

  float mrun = -INFINITY, lpart = 0.f;
  f32x16 o[4] = {};
  const int lswz = (q32 & 15) << 4;

  // K: linear rows with (row&15) slot XOR.  V: pair-interleaved (R9-verified).
#define STAGE_KV(kt_, bb)                                                                \
  {                                                                                      \
    const int kb0_ = (kt_) * 64;                                                         \
    _Pragma("unroll") for (int is = 0; is < 4; ++is) {                                   \
      int p = tid + is * 256;                                                            \
      int row = p >> 4, ch = p & 15;                                                     \
      int src = (ch * 16) ^ ((row & 15) << 4);                                           \
      GLOAD_LDS((const char*)(Kf + (size_t)(b * SEQ + kb0_ + row) * LDK + h * HDIM) +    \
                    src,                                                                 \
                KsB + (bb) * 16384 + p * 16);                                            \
    }                                                                                    \
    _Pragma("unroll") for (int is = 0; is < 4; ++is) {                                   \
      int p = tid + is * 256;                                                            \
      int row = p >> 4, u = (p & 15) ^ (row & 15);                                       \
      GLOAD_LDS(Vt + (size_t)(bh * HDIM + 2 * row + (u >> 3)) * SEQ + kb0_ +             \
                    (u & 7) * 8,                                                         \
                VsB + (bb) * 16384 + p * 16);                                            \
    }                                                                                    \
  }

#define INIT_SACC(kb)                                                                    \
  {                                                                                      \
    _Pragma("unroll") for (int r = 0; r < 8; ++r) {                                      \
      sacc[kb][r]     = (float)mk[2 * (kb)][r];                                          \
      sacc[kb][8 + r] = (float)mk[2 * (kb) + 1][r];                                      \
    }                                                                                    \
  }
#define QK_CHAIN(kb)                                                                     \
  {                                                                                      \
    const char* Kb_ = KsB + cur * 16384 + (kb) * 8192 + q32 * 256;                       \
    __builtin_amdgcn_s_setprio(1);                                                       \
    _Pragma("unroll") for (int ds = 0; ds < 8; ++ds) {                                   \
      bf16x8 kfr = *(const bf16x8*)(Kb_ + ((ds * 32 + hi * 16) ^ lswz));                 \
      sacc[kb] = MFMA32(kfr, qf[ds], sacc[kb]);                                          \
    }                                                                                    \
    __builtin_amdgcn_s_setprio(0);                                                       \
  }

  STAGE_KV(0, 0);
  __syncthreads();

  const int NT = SEQ / 64;                      // 32
  for (int kt = 0; kt < NT; ++kt) {
    const int cur = kt & 1;
    if (kt + 1 < NT) STAGE_KV(kt + 1, cur ^ 1);

    bf16x8 mk[4];
#pragma unroll
    for (int kb = 0; kb < 2; ++kb) {
      const size_t mo = (size_t)(kt * 2 + kb) * 65536;
      mk[2 * kb]     = *(const bf16x8*)(mQ + mo);
      mk[2 * kb + 1] = *(const bf16x8*)(mQ + mo + 8);
    }

    f32x16 sacc[2];
    INIT_SACC(0);
    QK_CHAIN(0);

#pragma unroll
    for (int kb = 0; kb < 2; ++kb) {
      if (kb < 1) {
        INIT_SACC(1);
        QK_CHAIN(1);
      }

      float a0 = fmaxf(fmaxf(sacc[kb][0], sacc[kb][1]), fmaxf(sacc[kb][2], sacc[kb][3]));
      float a1 = fmaxf(fmaxf(sacc[kb][4], sacc[kb][5]), fmaxf(sacc[kb][6], sacc[kb][7]));
      float a2 = fmaxf(fmaxf(sacc[kb][8], sacc[kb][9]), fmaxf(sacc[kb][10], sacc[kb][11]));
      float a3 = fmaxf(fmaxf(sacc[kb][12], sacc[kb][13]),
                       fmaxf(sacc[kb][14], sacc[kb][15]));
      float mx = fmaxf(fmaxf(a0, a1), fmaxf(a2, a3));
      mx = fmaxf(mx, __shfl_xor(mx, 32, 64));
      if (!__all(mx <= mrun + 11.5f)) {          // e^8-equivalent bound in base-2
        float mnew = fmaxf(mrun, mx);
        float corr = exp2_fast(mrun - mnew);
        mrun = mnew; lpart *= corr;
#pragma unroll
        for (int d0 = 0; d0 < 4; ++d0)
#pragma unroll
          for (int r = 0; r < 16; ++r) o[d0][r] *= corr;
      }

      float p_[16];
#pragma unroll
      for (int r = 0; r < 16; ++r) p_[r] = exp2_fast(sacc[kb][r] - mrun);
      {
        float t0 = (p_[0] + p_[1]) + (p_[2] + p_[3]);
        float t1 = (p_[4] + p_[5]) + (p_[6] + p_[7]);
        float t2 = (p_[8] + p_[9]) + (p_[10] + p_[11]);
        float t3 = (p_[12] + p_[13]) + (p_[14] + p_[15]);
        lpart += (t0 + t1) + (t2 + t3);
      }

      // PV with pair-interleaved V tile (R9-verified read formula)
#pragma unroll
      for (int s = 0; s < 2; ++s) {
        bf16x8 pav = pack_slice(p_ + 8 * s);
        const int gs = kb * 2 + s;              // 16-key slice within 64-key tile
        __builtin_amdgcn_s_setprio(1);
#pragma unroll
        for (int d0 = 0; d0 < 4; ++d0) {
          int vrow = d0 * 16 + (q32 >> 1);
          int slot = (((q32 & 1) << 3) + gs * 2 + hi) ^ (vrow & 15);
          bf16x8 vf = *(const bf16x8*)(VsB + cur * 16384 + vrow * 256 + slot * 16);
          o[d0] = MFMA32(vf, pav, o[d0]);
        }
        __builtin_amdgcn_s_setprio(0);
      }
    }
    __syncthreads();
  }
#undef STAGE_KV
#undef INIT_SACC
#undef QK_CHAIN

  float l = lpart + __shfl_xor(lpart, 32, 64);
  float rl = 1.f / l;
  bf16_t* aorow = AO + (size_t)(b * SEQ + qg) * HID + h * HDIM;
#pragma unroll
  for (int d0 = 0; d0 < 4; ++d0)
#pragma unroll
    for (int g = 0; g < 4; ++g) {
      unsigned lo = pk2(o[d0][4 * g + 0] * rl, o[d0][4 * g + 1] * rl);
      unsigned hi2 = pk2(o[d0][4 * g + 2] * rl, o[d0][4 * g + 3] * rl);
      int d = d0 * 32 + 8 * g + 4 * hi;
      *(unsigned*)(aorow + d) = lo;
      *(unsigned*)(aorow + d + 2) = hi2;
    }
}

// ---------------- launch ----------------
extern "C" void kernel_launch(void* const* d_in, const int* in_sizes, int n_in,
                              void* d_out, int out_size, void* d_ws, size_t ws_size,
                              hipStream_t stream) {
  const float* hidden = (const float*)d_in[0];
  const float* cost   = (const float*)d_in[1];
  const float* sint   = (const float*)d_in[2];
  const float* mask   = (const float*)d_in[3];
  const float* Wq     = (const float*)d_in[4];
  const float* Wk     = (const float*)d_in[5];
  const float* Wv     = (const float*)d_in[6];
  const float* Wo     = (const float*)d_in[7];
  float* out = (float*)d_out;
  char* ws = (char*)d_ws;

  bf16_t* Af    = (bf16_t*)(ws + 0);
  bf16_t* Wqb   = (bf16_t*)(ws + 16777216);
  bf16_t* Wvb   = (bf16_t*)(ws + 33554432);
  bf16_t* Wob   = (bf16_t*)(ws + 41943040);
  bf16_t* QK    = (bf16_t*)(ws + 50331648);
  bf16_t* maskP = (bf16_t*)(ws + 83886080);
  bf16_t* Vt    = (bf16_t*)(ws + 100663296);
  bf16_t* AO    = (bf16_t*)(ws + 16777216);

  cast_all<<<24576, 256, 0, stream>>>(hidden, Wq, Wk, Wv, Wo, Af, Wqb);

  gemm256_rope<<<256, 512, 0, stream>>>(Af, Wqb, QK, cost, sint, 4096, LDK, HID);
  gemm_v<<<512, 256, 0, stream>>>(Af, Wvb, Vt, 4096, HID, HID);

  mask_pack<<<dim3(64, 64, 2), 256, 0, stream>>>(mask, maskP);

  flash_fwd<<<512, 256, 0, stream>>>(QK, QK + 2048, Vt, maskP, AO);

  gemm_bt<<<512, 256, 0, stream>>>(AO, Wob, nullptr, out, 4096, HID, HID);
}

// Round 20
// 288.143 us; speedup vs baseline: 1.0258x; 1.0137x over previous
//
#include <hip/hip_runtime.h>
#include <hip/hip_bf16.h>
#include <math.h>

// B=2, S=2048, H=2048, NH=16, HD=128
#define SEQ 2048
#define HID 2048
#define NHEAD 16
#define HDIM 128
#define LDK 4096   // fused QK row stride

typedef __bf16 bf16_t;
typedef __bf16 bf16x2 __attribute__((ext_vector_type(2)));
typedef __bf16 bf16x4_t __attribute__((ext_vector_type(4)));
typedef __bf16 bf16x8 __attribute__((ext_vector_type(8)));
typedef float f32x4 __attribute__((ext_vector_type(4)));
typedef float f32x16 __attribute__((ext_vector_type(16)));
typedef unsigned u32x4 __attribute__((ext_vector_type(4)));

#define MFMA16(a, b, c) __builtin_amdgcn_mfma_f32_16x16x32_bf16(a, b, c, 0, 0, 0)
#define MFMA32(a, b, c) __builtin_amdgcn_mfma_f32_32x32x16_bf16(a, b, c, 0, 0, 0)
#define GLOAD_LDS(g, l) \
  __builtin_amdgcn_global_load_lds((const __attribute__((address_space(1))) void*)(g), \
                                   (__attribute__((address_space(3))) void*)(l), 16, 0, 0)

static __device__ inline unsigned pk2(float lo, float hi) {
  bf16x2 t; t[0] = (bf16_t)lo; t[1] = (bf16_t)hi;
  return __builtin_bit_cast(unsigned, t);
}

// native 2^x (v_exp_f32 computes exp2); avoids glibc __exp2f macro collision
static __device__ inline float exp2_fast(float x) {
  float r;
  asm("v_exp_f32 %0, %1" : "=v"(r) : "v"(x));
  return r;
}

// pack 8 p-values into the PV B-fragment via v_permlane32_swap (verified R13).
// Safe because the two operands hold DIFFERENT values and both outputs are used.
static __device__ inline bf16x8 pack_slice(const float* p) {
  unsigned A1 = pk2(p[0], p[1]);
  unsigned A2 = pk2(p[2], p[3]);
  unsigned B1 = pk2(p[4], p[5]);
  unsigned B2 = pk2(p[6], p[7]);
  asm("v_permlane32_swap_b32 %0, %1" : "+v"(A1), "+v"(B1));
  asm("v_permlane32_swap_b32 %0, %1" : "+v"(A2), "+v"(B2));
  u32x4 W = {A1, A2, B1, B2};
  return __builtin_bit_cast(bf16x8, W);
}

// ---------------- prep: casts (hidden + 4 weights) AND mask pack, one launch --------
// grid 32768: blk<8192 hidden cast; blk<24576 weight cast; else mask pack
// (mask[b][0][q][k] f32 -> maskP[b][kg][q][kl'] bf16 x log2e, MFMA C-reg order).
__global__ void prep_all(const float* __restrict__ hidden,
                         const float* __restrict__ wq, const float* __restrict__ wk,
                         const float* __restrict__ wv, const float* __restrict__ wo,
                         const float* __restrict__ mask,
                         bf16_t* __restrict__ hOut, bf16_t* __restrict__ wOut,
                         bf16_t* __restrict__ mp) {
  __shared__ float t[32][33];
  int blk = blockIdx.x;
  if (blk < 24576) {
    const float* src;
    bf16_t* dst;
    int i;
    if (blk < 8192) {
      src = hidden; dst = hOut;
      i = blk * 256 + threadIdx.x;
    } else {
      int w = (blk - 8192) >> 12;
      const float* srcs[4] = {wq, wk, wv, wo};
      src = srcs[w];
      dst = wOut + (size_t)w * (HID * HID);
      i = ((blk - 8192) & 4095) * 256 + threadIdx.x;
    }
    float4 v = ((const float4*)src)[i];
    bf16x4_t b;
    b[0] = (bf16_t)v.x; b[1] = (bf16_t)v.y; b[2] = (bf16_t)v.z; b[3] = (bf16_t)v.w;
    ((bf16x4_t*)dst)[i] = b;
  } else {
    const float L2E = 1.4426950408889634f;
    int mblk = blk - 24576;                    // 8192 blocks: 64 q x 64 k x 2 b
    int q0 = (mblk & 63) * 32;
    int k0 = ((mblk >> 6) & 63) * 32;
    int z = mblk >> 12;
    int tx = threadIdx.x & 31, ty = threadIdx.x >> 5;
    const float* mb = mask + (size_t)z * SEQ * SEQ;
#pragma unroll
    for (int j = 0; j < 4; ++j)
      t[ty + j * 8][tx] = mb[(size_t)(q0 + ty + j * 8) * SEQ + k0 + tx];
    __syncthreads();
    int r = tx & 15, hi = tx >> 4;
    int kl = (r & 3) + 8 * (r >> 2) + 4 * hi;
    bf16_t* ob = mp + ((size_t)(z * 64 + (k0 >> 5)) * 2048 + q0) * 32;
#pragma unroll
    for (int j = 0; j < 4; ++j) {
      int qloc = ty + j * 8;
      ob[(size_t)qloc * 32 + tx] = (bf16_t)(t[qloc][kl] * L2E);
    }
  }
}

// ---------------- 256x256 8-phase GEMM + fused RoPE epilogue (QK projection) -------
__global__ __launch_bounds__(512, 2) void gemm256_rope(
    const bf16_t* __restrict__ A, const bf16_t* __restrict__ Bw,
    bf16_t* __restrict__ Cb, const float* __restrict__ cosT,
    const float* __restrict__ sinT, int M, int N, int K) {
  __shared__ char smem[131072];
  const int tid = threadIdx.x, lane = tid & 63, wid = tid >> 6;
  const int wr = wid >> 2, wc = wid & 3;
  const int lr = lane & 15, lg = lane >> 4;
  const int xcd = blockIdx.x & 7, l = blockIdx.x >> 3;
  const int brow = (xcd >> 2) * 8 + (l >> 2);
  const int bcol = (xcd & 3) * 4 + (l & 3);
  const int NT = K >> 6;

  const bf16_t* Ab = A + (size_t)(brow * 256) * K;
  const bf16_t* Bb = Bw + (size_t)(bcol * 256) * K;

  f32x4 acc[8][4] = {};
  bf16x8 af[4], bfr[4];
  const int swz = (lg ^ ((lr >> 1) & 3)) << 4;

#define STAGE_HALF(t_, op, kh)                                                        \
  {                                                                                   \
    int tt = (t_) < NT ? (t_) : NT - 1;                                               \
    const bf16_t* gsrc = (op) ? Bb : Ab;                                              \
    char* ldst = smem + (tt & 1) * 65536 + (op) * 32768 + (kh) * 16384;               \
    _Pragma("unroll") for (int is = 0; is < 2; ++is) {                                \
      int p = tid + is * 512;                                                         \
      int row = p >> 2, ch = p & 3;                                                   \
      GLOAD_LDS(gsrc + (size_t)row * K + tt * 64 + (kh) * 32 +                        \
                    ((ch ^ ((row >> 1) & 3)) * 8),                                    \
                ldst + p * 16);                                                       \
    }                                                                                 \
  }

#define PHASE(cb, kh, mh, LOADB, STAGECALL, VM)                                       \
  {                                                                                   \
    _Pragma("unroll") for (int mf = 0; mf < 4; ++mf) {                                \
      int row = wr * 128 + (mh) * 64 + mf * 16 + lr;                                  \
      af[mf] = *(const bf16x8*)(smem + (cb) * 65536 + (kh) * 16384 + row * 64 + swz); \
    }                                                                                 \
    if (LOADB) {                                                                      \
      _Pragma("unroll") for (int nf = 0; nf < 4; ++nf) {                              \
        int row = wc * 64 + nf * 16 + lr;                                             \
        bfr[nf] = *(const bf16x8*)(smem + (cb) * 65536 + 32768 + (kh) * 16384 +       \
                                   row * 64 + swz);                                   \
      }                                                                               \
    }                                                                                 \
    STAGECALL;                                                                        \
    __builtin_amdgcn_s_barrier();                                                     \
    asm volatile("s_waitcnt lgkmcnt(0)" ::: "memory");                                \
    __builtin_amdgcn_sched_barrier(0);                                                \
    __builtin_amdgcn_s_setprio(1);                                                    \
    _Pragma("unroll") for (int mf = 0; mf < 4; ++mf)                                  \
      _Pragma("unroll") for (int nf = 0; nf < 4; ++nf)                                \
        acc[(mh) * 4 + mf][nf] = MFMA16(af[mf], bfr[nf], acc[(mh) * 4 + mf][nf]);     \
    __builtin_amdgcn_s_setprio(0);                                                    \
    if (VM) { asm volatile("s_waitcnt vmcnt(6)" ::: "memory"); }                      \
    __builtin_amdgcn_s_barrier();                                                     \
    __builtin_amdgcn_sched_barrier(0);                                                \
  }

  STAGE_HALF(0, 1, 0); STAGE_HALF(0, 0, 0); STAGE_HALF(0, 1, 1); STAGE_HALF(0, 0, 1);
  STAGE_HALF(1, 1, 0); STAGE_HALF(1, 0, 0); STAGE_HALF(1, 1, 1);
  asm volatile("s_waitcnt vmcnt(6)" ::: "memory");
  __builtin_amdgcn_s_barrier();
  __builtin_amdgcn_sched_barrier(0);

  const int NI = NT >> 1;
  for (int i = 0; i < NI; ++i) {
    const int t2 = 2 * i;
    PHASE(0, 0, 0, 1, STAGE_HALF(t2 + 1, 0, 1), 0);
    PHASE(0, 0, 1, 0, STAGE_HALF(t2 + 2, 1, 0), 0);
    PHASE(0, 1, 0, 1, STAGE_HALF(t2 + 2, 0, 0), 0);
    PHASE(0, 1, 1, 0, STAGE_HALF(t2 + 2, 1, 1), 1);
    PHASE(1, 0, 0, 1, STAGE_HALF(t2 + 2, 0, 1), 0);
    PHASE(1, 0, 1, 0, STAGE_HALF(t2 + 3, 1, 0), 0);
    PHASE(1, 1, 0, 1, STAGE_HALF(t2 + 3, 0, 0), 0);
    PHASE(1, 1, 1, 0, STAGE_HALF(t2 + 3, 1, 1), 1);
  }
#undef PHASE
#undef STAGE_HALF

  // ---- fused RoPE epilogue ----
  asm volatile("s_waitcnt vmcnt(0)" ::: "memory");
  __builtin_amdgcn_s_barrier();

  const int base = wid * 16384;
#pragma unroll
  for (int mi = 0; mi < 8; ++mi)
#pragma unroll
    for (int nf = 0; nf < 4; ++nf)
#pragma unroll
      for (int r = 0; r < 4; ++r)
        *(bf16_t*)(smem + base + ((mi * 4 + nf) * 4 + r) * 128 + lane * 2) =
            (bf16_t)acc[mi][nf][r];
  __syncthreads();

  const int pbase = (wid ^ 1) * 16384;
  const float SCALE = 0.12751569978848444f;  // log2(e)/sqrt(128) for Q columns
#pragma unroll
  for (int mi = 0; mi < 8; ++mi)
#pragma unroll
    for (int nf = 0; nf < 4; ++nf) {
      int col = bcol * 256 + wc * 64 + nf * 16 + lr;
      int d = col & 127;
      const float sc = (col < 2048) ? SCALE : 1.0f;
#pragma unroll
      for (int r = 0; r < 4; ++r) {
        int row = brow * 256 + wr * 128 + (mi >> 2) * 64 + (mi & 3) * 16 + lg * 4 + r;
        int s = row & (SEQ - 1);
        float part = (float)*(const bf16_t*)(smem + pbase +
                                             ((mi * 4 + nf) * 4 + r) * 128 + lane * 2);
        float cc = cosT[s * HDIM + d];
        float ss = sinT[s * HDIM + d];
        float own = acc[mi][nf][r];
        float ov = (d < 64) ? (own * cc - part * ss) : (own * cc + part * ss);
        Cb[(size_t)row * N + col] = (bf16_t)(ov * sc);
      }
    }
}

// ---------------- V GEMM + fused transpose epilogue: writes Vt[b][h][d][s] ---------
__global__ __launch_bounds__(256, 3) void gemm_v(
    const bf16_t* __restrict__ A, const bf16_t* __restrict__ Bw,
    bf16_t* __restrict__ Vt, int M, int N, int K) {
  __shared__ char smv[34816];
  bf16_t* As = (bf16_t*)smv;
  bf16_t* Bs = (bf16_t*)(smv + 16384);
  const int tid = threadIdx.x;
  const int lane = tid & 63, wid = tid >> 6;
  const int wr = wid >> 1, wc = wid & 1;
  const int lr = lane & 15, lg = lane >> 4;
  const int nwg = gridDim.x;
  const int lid = (blockIdx.x & 7) * (nwg >> 3) + (blockIdx.x >> 3);
  const int nbc = N >> 7;
  const int brow = lid / nbc, bcol = lid % nbc;

  f32x4 acc[4][4] = {};
  const int swz = lg ^ ((lr >> 1) & 3);

  const int srow = tid >> 2, sch = tid & 3;
#define GSTAGE(k0, bb)                                                                   \
  {                                                                                      \
    _Pragma("unroll") for (int is = 0; is < 2; ++is) {                                   \
      int row = srow + is * 64;                                                          \
      int g = (sch ^ ((row >> 1) & 3)) * 8;                                              \
      GLOAD_LDS(A + (size_t)(brow * 128 + row) * K + (k0) + g,                           \
                As + (bb) * 4096 + (row * 4 + sch) * 8);                                 \
      GLOAD_LDS(Bw + (size_t)(bcol * 128 + row) * K + (k0) + g,                          \
                Bs + (bb) * 4096 + (row * 4 + sch) * 8);                                 \
    }                                                                                    \
  }

  GSTAGE(0, 0);
  __syncthreads();

  const int nt = K / 32;
  for (int t = 0; t < nt; ++t) {
    const int cb = t & 1;
    if (t + 1 < nt) GSTAGE((t + 1) * 32, cb ^ 1);
    bf16x8 af[4], bfr[4];
#pragma unroll
    for (int m = 0; m < 4; ++m)
      af[m] = *(const bf16x8*)(As + cb * 4096 + (wr * 64 + m * 16 + lr) * 32 + swz * 8);
#pragma unroll
    for (int n = 0; n < 4; ++n)
      bfr[n] = *(const bf16x8*)(Bs + cb * 4096 + (wc * 64 + n * 16 + lr) * 32 + swz * 8);
#pragma unroll
    for (int m = 0; m < 4; ++m)
#pragma unroll
      for (int n = 0; n < 4; ++n)
        acc[m][n] = MFMA16(af[m], bfr[n], acc[m][n]);
    __syncthreads();
  }
#undef GSTAGE

  // ---- fused transpose epilogue ----
  bf16_t* tr = (bf16_t*)smv;                   // [128 d][136 s-capacity]
#pragma unroll
  for (int m = 0; m < 4; ++m)
#pragma unroll
    for (int n = 0; n < 4; ++n) {
      int d = wc * 64 + n * 16 + lr;
#pragma unroll
      for (int r = 0; r < 4; ++r) {
        int s = wr * 64 + m * 16 + lg * 4 + r;
        tr[d * 136 + s] = (bf16_t)acc[m][n][r];
      }
    }
  __syncthreads();

  const int b = brow >> 4, h = bcol;
  const int s0 = (brow & 15) * 128;
  bf16_t* vbase = Vt + ((size_t)(b * NHEAD + h) * HDIM) * SEQ + s0;
  const int dd = (lane >> 3);
  const int sl = (lane & 7) * 8;
#pragma unroll
  for (int it = 0; it < 4; ++it) {
    int d = wid * 32 + it * 8 + dd;
#pragma unroll
    for (int si = 0; si < 2; ++si) {
      int s = si * 64 + sl;
      bf16x8 v = *(const bf16x8*)(tr + d * 136 + s);
      *(bf16x8*)(vbase + (size_t)d * SEQ + s) = v;
    }
  }
}

// ---------------- GEMM: C = A * B^T, 2-phase double-buffered (128x128) -------------
__global__ __launch_bounds__(256, 3) void gemm_bt(
    const bf16_t* __restrict__ A, const bf16_t* __restrict__ Bw,
    bf16_t* __restrict__ Cb, float* __restrict__ Cf,
    int M, int N, int K) {
  __shared__ bf16_t As[2][128 * 32];
  __shared__ bf16_t Bs[2][128 * 32];
  const int tid = threadIdx.x;
  const int lane = tid & 63, wid = tid >> 6;
  const int wr = wid >> 1, wc = wid & 1;
  const int lr = lane & 15, lg = lane >> 4;
  const int nwg = gridDim.x;
  const int lid = (blockIdx.x & 7) * (nwg >> 3) + (blockIdx.x >> 3);
  const int nbc = N >> 7;
  const int brow = lid / nbc, bcol = lid % nbc;

  f32x4 acc[4][4] = {};
  const int swz = lg ^ ((lr >> 1) & 3);

  const int srow = tid >> 2, sch = tid & 3;
#define GSTAGE(k0, bb)                                                                   \
  {                                                                                      \
    _Pragma("unroll") for (int is = 0; is < 2; ++is) {                                   \
      int row = srow + is * 64;                                                          \
      int g = (sch ^ ((row >> 1) & 3)) * 8;                                              \
      GLOAD_LDS(A + (size_t)(brow * 128 + row) * K + (k0) + g,                           \
                &As[bb][(row * 4 + sch) * 8]);                                           \
      GLOAD_LDS(Bw + (size_t)(bcol * 128 + row) * K + (k0) + g,                          \
                &Bs[bb][(row * 4 + sch) * 8]);                                           \
    }                                                                                    \
  }

  GSTAGE(0, 0);
  __syncthreads();

  const int nt = K / 32;
  for (int t = 0; t < nt; ++t) {
    const int cb = t & 1;
    if (t + 1 < nt) GSTAGE((t + 1) * 32, cb ^ 1);
    bf16x8 af[4], bfr[4];
#pragma unroll
    for (int m = 0; m < 4; ++m)
      af[m] = *(const bf16x8*)(&As[cb][(wr * 64 + m * 16 + lr) * 32 + swz * 8]);
#pragma unroll
    for (int n = 0; n < 4; ++n)
      bfr[n] = *(const bf16x8*)(&Bs[cb][(wc * 64 + n * 16 + lr) * 32 + swz * 8]);
#pragma unroll
    for (int m = 0; m < 4; ++m)
#pragma unroll
      for (int n = 0; n < 4; ++n)
        acc[m][n] = MFMA16(af[m], bfr[n], acc[m][n]);
    __syncthreads();
  }
#undef GSTAGE

#pragma unroll
  for (int m = 0; m < 4; ++m)
#pragma unroll
    for (int n = 0; n < 4; ++n)
#pragma unroll
      for (int r = 0; r < 4; ++r) {
        int row = brow * 128 + wr * 64 + m * 16 + lg * 4 + r;
        int col = bcol * 128 + wc * 64 + n * 16 + lr;
        float v = acc[m][n][r];
        if (Cf) Cf[(size_t)row * N + col] = v;
        else    Cb[(size_t)row * N + col] = (bf16_t)v;
      }
}

// ---------------- flash attention fwd v9 (R19-verified best) ------------------------
// 4 waves x 32q, KVBLK=64 dbuf (64 KB LDS, 2 blocks/CU). K [64][256B] (row&15) XOR;
// V pair-interleaved [64][256B]. v7 softmax/pack/pipeline (exp2, permlane pack).
__global__ __launch_bounds__(256, 2) void flash_fwd(
    const bf16_t* __restrict__ Qf, const bf16_t* __restrict__ Kf,
    const bf16_t* __restrict__ Vt, const bf16_t* __restrict__ maskP,
    bf16_t* __restrict__ AO) {
  __shared__ char smem[65536];           // K 2x16K | V 2x16K
  char* KsB = smem;
  char* VsB = smem + 32768;
  const int tid = threadIdx.x, lane = tid & 63, wid = tid >> 6;
  const int q32 = lane & 31, hi = lane >> 5;

  const int x = blockIdx.x;
  const int bh = x & 31, qt = x >> 5;          // qt 0..15
  const int b = bh >> 4, h = bh & 15;
  const int qg = qt * 128 + wid * 32 + q32;

  bf16x8 qf[8];
  const bf16_t* qptr = Qf + (size_t)(b * SEQ + qg) * LDK + h * HDIM + hi * 8;
#pragma unroll
  for (int ds = 0; ds < 8; ++ds) qf[ds] = *(const bf16x8*)(qptr + ds * 16);

  const bf16_t* mQ = maskP + (size_t)b * 64 * 65536 + (size_t)qg * 32 + hi * 16;

  float mrun = -INFINITY, lpart = 0.f;
  f32x16 o[4] = {};
  const int lswz = (q32 & 15) << 4;

#define STAGE_KV(kt_, bb)                                                                \
  {                                                                                      \
    const int kb0_ = (kt_) * 64;                                                         \
    _Pragma("unroll") for (int is = 0; is < 4; ++is) {                                   \
      int p = tid + is * 256;                                                            \
      int row = p >> 4, ch = p & 15;                                                     \
      int src = (ch * 16) ^ ((row & 15) << 4);                                           \
      GLOAD_LDS((const char*)(Kf + (size_t)(b * SEQ + kb0_ + row) * LDK + h * HDIM) +    \
                    src,                                                                 \
                KsB + (bb) * 16384 + p * 16);                                            \
    }                                                                                    \
    _Pragma("unroll") for (int is = 0; is < 4; ++is) {                                   \
      int p = tid + is * 256;                                                            \
      int row = p >> 4, u = (p & 15) ^ (row & 15);                                       \
      GLOAD_LDS(Vt + (size_t)(bh * HDIM + 2 * row + (u >> 3)) * SEQ + kb0_ +             \
                    (u & 7) * 8,                                                         \
                VsB + (bb) * 16384 + p * 16);                                            \
    }                                                                                    \
  }

#define INIT_SACC(kb)                                                                    \
  {                                                                                      \
    _Pragma("unroll") for (int r = 0; r < 8; ++r) {                                      \
      sacc[kb][r]     = (float)mk[2 * (kb)][r];                                          \
      sacc[kb][8 + r] = (float)mk[2 * (kb) + 1][r];                                      \
    }                                                                                    \
  }
#define QK_CHAIN(kb)                                                                     \
  {                                                                                      \
    const char* Kb_ = KsB + cur * 16384 + (kb) * 8192 + q32 * 256;                       \
    __builtin_amdgcn_s_setprio(1);                                                       \
    _Pragma("unroll") for (int ds = 0; ds < 8; ++ds) {                                   \
      bf16x8 kfr = *(const bf16x8*)(Kb_ + ((ds * 32 + hi * 16) ^ lswz));                 \
      sacc[kb] = MFMA32(kfr, qf[ds], sacc[kb]);                                          \
    }                                                                                    \
    __builtin_amdgcn_s_setprio(0);                                                       \
  }

  STAGE_KV(0, 0);
  __syncthreads();

  const int NT = SEQ / 64;                      // 32
  for (int kt = 0; kt < NT; ++kt) {
    const int cur = kt & 1;
    if (kt + 1 < NT) STAGE_KV(kt + 1, cur ^ 1);

    bf16x8 mk[4];
#pragma unroll
    for (int kb = 0; kb < 2; ++kb) {
      const size_t mo = (size_t)(kt * 2 + kb) * 65536;
      mk[2 * kb]     = *(const bf16x8*)(mQ + mo);
      mk[2 * kb + 1] = *(const bf16x8*)(mQ + mo + 8);
    }

    f32x16 sacc[2];
    INIT_SACC(0);
    QK_CHAIN(0);

#pragma unroll
    for (int kb = 0; kb < 2; ++kb) {
      if (kb < 1) {
        INIT_SACC(1);
        QK_CHAIN(1);
      }

      float a0 = fmaxf(fmaxf(sacc[kb][0], sacc[kb][1]), fmaxf(sacc[kb][2], sacc[kb][3]));
      float a1 = fmaxf(fmaxf(sacc[kb][4], sacc[kb][5]), fmaxf(sacc[kb][6], sacc[kb][7]));
      float a2 = fmaxf(fmaxf(sacc[kb][8], sacc[kb][9]), fmaxf(sacc[kb][10], sacc[kb][11]));
      float a3 = fmaxf(fmaxf(sacc[kb][12], sacc[kb][13]),
                       fmaxf(sacc[kb][14], sacc[kb][15]));
      float mx = fmaxf(fmaxf(a0, a1), fmaxf(a2, a3));
      mx = fmaxf(mx, __shfl_xor(mx, 32, 64));
      if (!__all(mx <= mrun + 11.5f)) {          // e^8-equivalent bound in base-2
        float mnew = fmaxf(mrun, mx);
        float corr = exp2_fast(mrun - mnew);
        mrun = mnew; lpart *= corr;
#pragma unroll
        for (int d0 = 0; d0 < 4; ++d0)
#pragma unroll
          for (int r = 0; r < 16; ++r) o[d0][r] *= corr;
      }

      float p_[16];
#pragma unroll
      for (int r = 0; r < 16; ++r) p_[r] = exp2_fast(sacc[kb][r] - mrun);
      {
        float t0 = (p_[0] + p_[1]) + (p_[2] + p_[3]);
        float t1 = (p_[4] + p_[5]) + (p_[6] + p_[7]);
        float t2 = (p_[8] + p_[9]) + (p_[10] + p_[11]);
        float t3 = (p_[12] + p_[13]) + (p_[14] + p_[15]);
        lpart += (t0 + t1) + (t2 + t3);
      }

      // PV with pair-interleaved V tile (R9-verified read formula)
#pragma unroll
      for (int s = 0; s < 2; ++s) {
        bf16x8 pav = pack_slice(p_ + 8 * s);
        const int gs = kb * 2 + s;              // 16-key slice within 64-key tile
        __builtin_amdgcn_s_setprio(1);
#pragma unroll
        for (int d0 = 0; d0 < 4; ++d0) {
          int vrow = d0 * 16 + (q32 >> 1);
          int slot = (((q32 & 1) << 3) + gs * 2 + hi) ^ (vrow & 15);
          bf16x8 vf = *(const bf16x8*)(VsB + cur * 16384 + vrow * 256 + slot * 16);
          o[d0] = MFMA32(vf, pav, o[d0]);
        }
        __builtin_amdgcn_s_setprio(0);
      }
    }
    __syncthreads();
  }
#undef STAGE_KV
#undef INIT_SACC
#undef QK_CHAIN

  float l = lpart + __shfl_xor(lpart, 32, 64);
  float rl = 1.f / l;
  bf16_t* aorow = AO + (size_t)(b * SEQ + qg) * HID + h * HDIM;
#pragma unroll
  for (int d0 = 0; d0 < 4; ++d0)
#pragma unroll
    for (int g = 0; g < 4; ++g) {
      unsigned lo = pk2(o[d0][4 * g + 0] * rl, o[d0][4 * g + 1] * rl);
      unsigned hi2 = pk2(o[d0][4 * g + 2] * rl, o[d0][4 * g + 3] * rl);
      int d = d0 * 32 + 8 * g + 4 * hi;
      *(unsigned*)(aorow + d) = lo;
      *(unsigned*)(aorow + d + 2) = hi2;
    }
}

// ---------------- launch ----------------
extern "C" void kernel_launch(void* const* d_in, const int* in_sizes, int n_in,
                              void* d_out, int out_size, void* d_ws, size_t ws_size,
                              hipStream_t stream) {
  const float* hidden = (const float*)d_in[0];
  const float* cost   = (const float*)d_in[1];
  const float* sint   = (const float*)d_in[2];
  const float* mask   = (const float*)d_in[3];
  const float* Wq     = (const float*)d_in[4];
  const float* Wk     = (const float*)d_in[5];
  const float* Wv     = (const float*)d_in[6];
  const float* Wo     = (const float*)d_in[7];
  float* out = (float*)d_out;
  char* ws = (char*)d_ws;

  bf16_t* Af    = (bf16_t*)(ws + 0);
  bf16_t* Wqb   = (bf16_t*)(ws + 16777216);
  bf16_t* Wvb   = (bf16_t*)(ws + 33554432);
  bf16_t* Wob   = (bf16_t*)(ws + 41943040);
  bf16_t* QK    = (bf16_t*)(ws + 50331648);
  bf16_t* maskP = (bf16_t*)(ws + 83886080);
  bf16_t* Vt    = (bf16_t*)(ws + 100663296);
  bf16_t* AO    = (bf16_t*)(ws + 16777216);

  // casts + mask pack in one launch
  prep_all<<<32768, 256, 0, stream>>>(hidden, Wq, Wk, Wv, Wo, mask, Af, Wqb, maskP);

  gemm256_rope<<<256, 512, 0, stream>>>(Af, Wqb, QK, cost, sint, 4096, LDK, HID);
  gemm_v<<<512, 256, 0, stream>>>(Af, Wvb, Vt, 4096, HID, HID);

  flash_fwd<<<512, 256, 0, stream>>>(QK, QK + 2048, Vt, maskP, AO);

  gemm_bt<<<512, 256, 0, stream>>>(AO, Wob, nullptr, out, 4096, HID, HID);
}